// Round 1
// baseline (2020.949 us; speedup 1.0000x reference)
//
#include <hip/hip_runtime.h>

// ---------------------------------------------------------------------------
// Att_MambaLayer: full-graph f32 implementation.
// Shapes: B=4, C=256, H=W=32, N=l=1024, NH=2, dh=128, DI=512, DS=16, DTR=16.
// All activations kept in (b, seq, chan) layout so GEMM inputs are row-major.
// ---------------------------------------------------------------------------

#define LOG2E 1.4426950408889634f

// ---- workspace layout (f32 element offsets) -------------------------------
static const long OFF_W1T  = 0;         // 2304*256 = 589,824 (conv1 weights^T)
static const long OFF_PB   = 589824;    // 3 branches * 44,544 packed params
static const long BRS      = 44544;
// per-branch pack: 0 cw(2048) | 2048 cb(512) | 2560 xpw(24576) | 27136 dtw(8192)
//                  35328 dtb(512) | 35840 Aln(8192) | 44032 D(512)
static const long OFF_XCT  = 750000;    // (b,n,256) conv1 out / LN in-place
static const long OFF_R1   = 1800000;   // 12.6M reuse region
static const long OFF_HS   = 14400000;  // (b,n,256) o-proj out (mamba hs)
static const long OFF_XZ   = 15450000;  // (b,l,1024)
static const long OFF_XDBL = 19650000;  // [3][4096][48]
static const long OFF_Y    = 20250000;  // [12][1024][512]
static const long OFF_COMB = 26550000;  // (b,l,512)
// region R1 tenants:
//  attn phase : Q(+0) K(+1048576) V(+2097152) SC(+3145728, 8.39M) ATT(+11534336)
//  mamba phase: XMC(+0, 6.29M) DT(+6291456, 6.29M)
//  tail phase : XMB(+0) XM2(+1048576) XP(+2097152) XF(+3145728)

// ---------------------------------------------------------------------------
__device__ __forceinline__ float block_reduce256(float v, int op) {
  #pragma unroll
  for (int m = 32; m; m >>= 1) {
    float o = __shfl_xor(v, m);
    v = op ? fmaxf(v, o) : v + o;
  }
  __shared__ float sm[4];
  if ((threadIdx.x & 63) == 0) sm[threadIdx.x >> 6] = v;
  __syncthreads();
  v = op ? fmaxf(fmaxf(sm[0], sm[1]), fmaxf(sm[2], sm[3]))
         : (sm[0] + sm[1] + sm[2] + sm[3]);
  __syncthreads();
  return v;
}

// ---- param packing --------------------------------------------------------
__global__ __launch_bounds__(256) void pack_w1t_k(const float* __restrict__ w,
                                                  float* __restrict__ w1t) {
  int j = blockIdx.x, co = threadIdx.x;          // j = ci*9+kh*3+kw
  w1t[j * 256 + co] = w[co * 2304 + j];
}

__global__ __launch_bounds__(256) void pack_branch_k(
    float* __restrict__ dst, const float* __restrict__ cw,
    const float* __restrict__ cb, const float* __restrict__ xpw,
    const float* __restrict__ dtw, const float* __restrict__ dtb,
    const float* __restrict__ Alog, const float* __restrict__ Dv) {
  int t = blockIdx.x * 256 + threadIdx.x;        // < 44,544
  if (t < 2048) dst[t] = cw[t];
  else if (t < 2560) dst[t] = cb[t - 2048];
  else if (t < 27136) dst[t] = xpw[t - 2560];
  else if (t < 35328) dst[t] = dtw[t - 27136];
  else if (t < 35840) dst[t] = dtb[t - 35328];
  else if (t < 44032) dst[t] = -expf(Alog[t - 35840]) * LOG2E;
  else if (t < 44544) dst[t] = Dv[t - 44032];
}

// ---- 3x3 conv (C=256->256, pad 1), NHWC output (b,n,co) -------------------
// mode 0: input = x (NCHW) viewed through the transpose(0,2,1,3)-reshape
//         shuffle, no activation (feeds LayerNorm).
// mode 1: input = NHWC buffer (b,n,ci), relu epilogue.
__global__ __launch_bounds__(256) void conv3x3_k(
    const float* __restrict__ in, const float* __restrict__ w1t,
    const float* __restrict__ bias, float* __restrict__ out, int mode) {
  __shared__ float patch[3 * 256 * 20];          // [kh][ci][w0-1 .. w0+16] pad20
  int w0 = blockIdx.x * 16;
  int bh = blockIdx.y;
  int b = bh >> 5, h0 = bh & 31;
  int tid = threadIdx.x;

  if (mode == 0) {
    for (int t = tid; t < 3 * 256 * 18; t += 256) {
      int wi = t % 18; int r = t / 18; int ci = r & 255; int kh = r >> 8;
      int hh = h0 + kh - 1, wg = w0 + wi - 1;
      float v = 0.f;
      if ((unsigned)hh < 32u && (unsigned)wg < 32u) {
        int idx = ci * 32 + hh;                  // x_flat[ci,hh] = x[idx&255, idx>>8]
        v = in[((long)b << 18) + ((long)(idx & 255) << 10) + ((idx >> 8) << 5) + wg];
      }
      patch[(kh * 256 + ci) * 20 + wi] = v;
    }
  } else {
    for (int t = tid; t < 3 * 256 * 18; t += 256) {
      int ci = t & 255; int r = t >> 8; int wi = r % 18; int kh = r / 18;
      int hh = h0 + kh - 1, wg = w0 + wi - 1;
      float v = 0.f;
      if ((unsigned)hh < 32u && (unsigned)wg < 32u)
        v = in[(((long)b << 10) + (hh << 5) + wg) * 256 + ci];
      patch[(kh * 256 + ci) * 20 + wi] = v;
    }
  }
  __syncthreads();

  float acc[16] = {};
  int co = tid;
  for (int ci = 0; ci < 256; ++ci) {
    #pragma unroll
    for (int kh = 0; kh < 3; ++kh) {
      const float* pr = &patch[(kh * 256 + ci) * 20];
      float p[20];
      #pragma unroll
      for (int q = 0; q < 5; ++q) {
        float4 f = ((const float4*)pr)[q];
        p[q * 4] = f.x; p[q * 4 + 1] = f.y; p[q * 4 + 2] = f.z; p[q * 4 + 3] = f.w;
      }
      const float* wp = &w1t[(ci * 9 + kh * 3) * 256 + co];
      float wv0 = wp[0], wv1 = wp[256], wv2 = wp[512];
      #pragma unroll
      for (int w = 0; w < 16; ++w)
        acc[w] = fmaf(p[w], wv0, fmaf(p[w + 1], wv1, fmaf(p[w + 2], wv2, acc[w])));
    }
  }
  float bb = bias[co];
  #pragma unroll
  for (int w = 0; w < 16; ++w) {
    float v = acc[w] + bb;
    if (mode) v = fmaxf(v, 0.f);
    out[(((long)b << 10) + (h0 << 5) + (w0 + w)) * 256 + co] = v;
  }
}

// ---- LayerNorm over channel dim (rows of 256), in place -------------------
__global__ __launch_bounds__(256) void layernorm_k(float* __restrict__ x,
                                                   const float* __restrict__ w,
                                                   const float* __restrict__ b) {
  float* p = x + (long)blockIdx.x * 256;
  float v = p[threadIdx.x];
  float mean = block_reduce256(v, 0) * (1.f / 256.f);
  float d = v - mean;
  float var = block_reduce256(d * d, 0) * (1.f / 256.f);
  p[threadIdx.x] = d * rsqrtf(var + 1e-5f) * w[threadIdx.x] + b[threadIdx.x];
}

// ---- softmax over rows of 1024 --------------------------------------------
__global__ __launch_bounds__(256) void softmax_k(float* __restrict__ S) {
  float* p = S + (long)blockIdx.x * 1024;
  float4 v = ((float4*)p)[threadIdx.x];
  float m = fmaxf(fmaxf(v.x, v.y), fmaxf(v.z, v.w));
  m = block_reduce256(m, 1);
  v.x = expf(v.x - m); v.y = expf(v.y - m);
  v.z = expf(v.z - m); v.w = expf(v.w - m);
  float s = block_reduce256(v.x + v.y + v.z + v.w, 0);
  float inv = 1.f / s;
  v.x *= inv; v.y *= inv; v.z *= inv; v.w *= inv;
  ((float4*)p)[threadIdx.x] = v;
}

// ---- generic strided batched GEMM: Out[m,n] = act(alpha*sum_k A*B + bias) --
// act: 0 none, 1 relu, 2 softplus
__global__ __launch_bounds__(256) void gemm_k(
    const float* __restrict__ A, const float* __restrict__ B,
    const float* __restrict__ bias, float* __restrict__ Out,
    int M, int N, int K,
    int a_sm, int a_sk, int b_sn, int b_sk, int o_sm,
    int zdiv, long a_zb, long a_zh, long b_zb, long b_zh, long o_zb, long o_zh,
    long bias_zb, float alpha, int act) {
  int z = blockIdx.z, zb = z / zdiv, zh = z % zdiv;
  const float* Ab = A + zb * a_zb + zh * a_zh;
  const float* Bb = B + zb * b_zb + zh * b_zh;
  const float* biasb = bias ? (bias + zb * bias_zb) : nullptr;
  float* Ob = Out + zb * o_zb + zh * o_zh;
  __shared__ float As[16][68];
  __shared__ float Bs[16][68];
  int m0 = blockIdx.x * 64, n0 = blockIdx.y * 64;
  int tid = threadIdx.x;
  int tm = tid >> 4, tn = tid & 15;
  float acc[4][4] = {};
  for (int k0 = 0; k0 < K; k0 += 16) {
    #pragma unroll
    for (int it = 0; it < 4; ++it) {
      int i = tid + it * 256;
      // A tile: pick decomposition so the fast-moving index is the unit-stride one
      if (a_sk == 1) {
        int rr = i >> 4, kk = i & 15;
        int gm = m0 + rr, gk = k0 + kk;
        float av = 0.f;
        if (gm < M && gk < K) av = Ab[(long)gm * a_sm + gk];
        As[kk][rr] = av;
      } else {
        int rr = i & 63, kk = i >> 6;
        int gm = m0 + rr, gk = k0 + kk;
        float av = 0.f;
        if (gm < M && gk < K) av = Ab[(long)gm * a_sm + (long)gk * a_sk];
        As[kk][rr] = av;
      }
      if (b_sk == 1) {
        int rr = i >> 4, kk = i & 15;
        int gn = n0 + rr, gk = k0 + kk;
        float bv = 0.f;
        if (gn < N && gk < K) bv = Bb[(long)gn * b_sn + gk];
        Bs[kk][rr] = bv;
      } else {
        int rr = i & 63, kk = i >> 6;
        int gn = n0 + rr, gk = k0 + kk;
        float bv = 0.f;
        if (gn < N && gk < K) bv = Bb[(long)gn * b_sn + (long)gk * b_sk];
        Bs[kk][rr] = bv;
      }
    }
    __syncthreads();
    #pragma unroll
    for (int kk = 0; kk < 16; ++kk) {
      float ar[4], br_[4];
      #pragma unroll
      for (int q = 0; q < 4; ++q) ar[q] = As[kk][tm * 4 + q];
      #pragma unroll
      for (int q = 0; q < 4; ++q) br_[q] = Bs[kk][tn * 4 + q];
      #pragma unroll
      for (int qi = 0; qi < 4; ++qi)
        #pragma unroll
        for (int qj = 0; qj < 4; ++qj)
          acc[qi][qj] = fmaf(ar[qi], br_[qj], acc[qi][qj]);
    }
    __syncthreads();
  }
  #pragma unroll
  for (int qi = 0; qi < 4; ++qi) {
    int gm = m0 + tm * 4 + qi;
    if (gm >= M) continue;
    #pragma unroll
    for (int qj = 0; qj < 4; ++qj) {
      int gn = n0 + tn * 4 + qj;
      if (gn >= N) continue;
      float v = acc[qi][qj] * alpha + (biasb ? biasb[gn] : 0.f);
      if (act == 1) v = fmaxf(v, 0.f);
      else if (act == 2) v = (v > 30.f) ? v : log1pf(expf(v));
      Ob[(long)gm * o_sm + gn] = v;
    }
  }
}

// ---- branch sequence index map --------------------------------------------
__device__ __forceinline__ int brmap(int br, int j) {
  if (br == 0) return j;
  if (br == 1) return 1023 - j;
  return ((j & 15) << 6) | (j >> 4);   // NSL=16 shuffle (involution pair)
}

// ---- causal depthwise conv1d (k=4) + silu, all 3 branches -----------------
// out layout: [(br*4+b)][j][512]
__global__ __launch_bounds__(256) void cconv_k(const float* __restrict__ xz,
                                               const float* __restrict__ pk,
                                               float* __restrict__ xmc) {
  long t = (long)blockIdx.x * 256 + threadIdx.x;   // < 6,291,456
  int d = (int)(t & 511);
  long r = t >> 9;
  int j = (int)(r & 1023);
  int bb = (int)(r >> 10);
  int b = bb & 3, br = bb >> 2;
  const float* pb = pk + (long)br * BRS;
  float acc = pb[2048 + d];                        // cb
  #pragma unroll
  for (int tap = 0; tap < 4; ++tap) {
    int jj = j - 3 + tap;
    if (jj >= 0) {
      int l = brmap(br, jj);
      acc = fmaf(xz[(((long)b << 10) + l) * 1024 + d], pb[d * 4 + tap], acc);
    }
  }
  float sig = 1.f / (1.f + expf(-acc));
  xmc[t] = acc * sig;
}

// ---- selective scan: 16 lanes per (b,d) row, one state n per lane ---------
__global__ __launch_bounds__(64) void scan_k(
    const float* __restrict__ xmc, const float* __restrict__ dt,
    const float* __restrict__ xdbl, const float* __restrict__ xz,
    const float* __restrict__ pk, float* __restrict__ y) {
  int br = blockIdx.y;
  int grp = blockIdx.x * 4 + (threadIdx.x >> 4);   // 2048 (b,d) rows
  int n = threadIdx.x & 15;
  int d = grp & 511, b = grp >> 9;
  const float* pb = pk + (long)br * BRS;
  float Aln = pb[35840 + d * 16 + n];              // A[d,n]*log2e (negative)
  float Dv = pb[44032 + d];
  long mbase = ((long)(br * 4 + b)) << 19;         // *1024*512
  long xdb = (long)br * 196608 + (long)b * 1024 * 48;
  long xzb = ((long)b << 20) + 512 + d;
  float s = 0.f;
  for (int j = 0; j < 1024; ++j) {
    long o = mbase + ((long)j << 9) + d;
    float delta = dt[o];
    float u = xmc[o];
    long xo = xdb + (long)j * 48;
    float Bv = xdbl[xo + 16 + n];
    float Cv = xdbl[xo + 32 + n];
    float dA = exp2f(delta * Aln);
    s = fmaf(dA, s, delta * u * Bv);
    float p = s * Cv;
    p += __shfl_xor(p, 1);
    p += __shfl_xor(p, 2);
    p += __shfl_xor(p, 4);
    p += __shfl_xor(p, 8);
    int l = brmap(br, j);
    float zv = xz[xzb + ((long)l << 10)];
    float sig = 1.f / (1.f + expf(-zv));
    float yv = (p + Dv * u) * (zv * sig);
    if (n == 0) y[o] = yv;
  }
}

// ---- combine the 3 branch outputs into comb (b,l,512) ---------------------
__global__ __launch_bounds__(256) void combine_k(const float* __restrict__ y,
                                                 float* __restrict__ comb) {
  long t = (long)blockIdx.x * 256 + threadIdx.x;   // < 2,097,152
  int d = (int)(t & 511);
  long r = t >> 9;
  int l = (int)(r & 1023);
  int b = (int)(r >> 10);
  int j2 = ((l & 63) << 4) | (l >> 6);             // inverse of NSL shuffle
  float v = y[(((long)b << 10) + l) * 512 + d]
          + y[(((long)(4 + b) << 10) + (1023 - l)) * 512 + d]
          + y[(((long)(8 + b) << 10) + j2) * 512 + d];
  comb[t] = v;
}

// ---- depthwise 3x3 conv + residual add, writes NCHW output ----------------
__global__ __launch_bounds__(256) void dw_k(const float* __restrict__ xf,
                                            const float* __restrict__ dww,
                                            const float* __restrict__ dwb,
                                            const float* __restrict__ x,
                                            float* __restrict__ out) {
  int t = blockIdx.x;                              // (b,h): 128
  int b = t >> 5, h = t & 31;
  int c = threadIdx.x;
  float wv[9];
  #pragma unroll
  for (int k = 0; k < 9; ++k) wv[k] = dww[c * 9 + k];
  float bb = dwb[c];
  for (int w = 0; w < 32; ++w) {
    float acc = bb;
    #pragma unroll
    for (int kh = 0; kh < 3; ++kh) {
      int hh = h + kh - 1;
      if ((unsigned)hh >= 32u) continue;
      #pragma unroll
      for (int kw = 0; kw < 3; ++kw) {
        int ww = w + kw - 1;
        if ((unsigned)ww >= 32u) continue;
        acc = fmaf(xf[(((long)b << 10) + (hh << 5) + ww) * 256 + c],
                   wv[kh * 3 + kw], acc);
      }
    }
    long oi = (((long)b * 256 + c) * 32 + h) * 32 + w;
    out[oi] = acc + x[oi];
  }
}

// ---------------------------------------------------------------------------
extern "C" void kernel_launch(void* const* d_in, const int* in_sizes, int n_in,
                              void* d_out, int out_size, void* d_ws, size_t ws_size,
                              hipStream_t stream) {
  (void)in_sizes; (void)n_in; (void)out_size; (void)ws_size;
  const float* x    = (const float*)d_in[0];
  const float* p1w  = (const float*)d_in[1];
  const float* p1b  = (const float*)d_in[2];
  const float* p2w  = (const float*)d_in[3];
  const float* p2b  = (const float*)d_in[4];
  const float* nw   = (const float*)d_in[5];
  const float* nb   = (const float*)d_in[6];
  const float* qw   = (const float*)d_in[7];
  const float* qb   = (const float*)d_in[8];
  const float* kw   = (const float*)d_in[9];
  const float* kb   = (const float*)d_in[10];
  const float* vw   = (const float*)d_in[11];
  const float* vb   = (const float*)d_in[12];
  const float* ow   = (const float*)d_in[13];
  const float* ob   = (const float*)d_in[14];
  const float* fc1w = (const float*)d_in[15];
  const float* fc1b = (const float*)d_in[16];
  const float* dww  = (const float*)d_in[17];
  const float* dwb  = (const float*)d_in[18];
  const float* inw  = (const float*)d_in[19];
  const float* cw   = (const float*)d_in[20];
  const float* cb   = (const float*)d_in[21];
  const float* cbw  = (const float*)d_in[22];
  const float* cbb  = (const float*)d_in[23];
  const float* csw  = (const float*)d_in[24];
  const float* csb  = (const float*)d_in[25];
  const float* xpw  = (const float*)d_in[26];
  const float* xpbw = (const float*)d_in[27];
  const float* xpsw = (const float*)d_in[28];
  const float* dtw  = (const float*)d_in[29];
  const float* dtb  = (const float*)d_in[30];
  const float* dtbw = (const float*)d_in[31];
  const float* dtbb = (const float*)d_in[32];
  const float* dtsw = (const float*)d_in[33];
  const float* dtsb = (const float*)d_in[34];
  const float* Alog = (const float*)d_in[35];
  const float* Ablog= (const float*)d_in[36];
  const float* Aslog= (const float*)d_in[37];
  const float* Dv   = (const float*)d_in[38];
  const float* Dbv  = (const float*)d_in[39];
  const float* Dsv  = (const float*)d_in[40];
  const float* outw = (const float*)d_in[41];
  float* out = (float*)d_out;

  float* ws = (float*)d_ws;
  float* W1T = ws + OFF_W1T;
  float* PB  = ws + OFF_PB;
  float* XCT = ws + OFF_XCT;
  float* R1  = ws + OFF_R1;
  float* Qb  = R1;
  float* Kb  = R1 + 1048576;
  float* Vb  = R1 + 2097152;
  float* SC  = R1 + 3145728;
  float* ATT = R1 + 11534336;
  float* XMC = R1;                 // mamba phase reuse
  float* DT  = R1 + 6291456;
  float* XMB = R1;                 // tail phase reuse
  float* XM2 = R1 + 1048576;
  float* XP  = R1 + 2097152;
  float* XF  = R1 + 3145728;
  float* HS  = ws + OFF_HS;
  float* XZ  = ws + OFF_XZ;
  float* XDBL= ws + OFF_XDBL;
  float* Y   = ws + OFF_Y;
  float* COMB= ws + OFF_COMB;

  auto gemm = [&](const float* A, const float* Bm, const float* bias, float* Out,
                  int M, int N, int K,
                  int a_sm, int a_sk, int b_sn, int b_sk, int o_sm,
                  int nz, int zdiv,
                  long a_zb, long a_zh, long b_zb, long b_zh, long o_zb, long o_zh,
                  long bias_zb, float alpha, int act) {
    dim3 g((M + 63) / 64, (N + 63) / 64, nz);
    gemm_k<<<g, 256, 0, stream>>>(A, Bm, bias, Out, M, N, K,
                                  a_sm, a_sk, b_sn, b_sk, o_sm, zdiv,
                                  a_zb, a_zh, b_zb, b_zh, o_zb, o_zh, bias_zb,
                                  alpha, act);
  };

  // 0) pack params (re-done every call; cheap, keeps graph-capture legal)
  pack_w1t_k<<<2304, 256, 0, stream>>>(p1w, W1T);
  pack_branch_k<<<174, 256, 0, stream>>>(PB + 0 * BRS, cw, cb, xpw, dtw, dtb, Alog, Dv);
  pack_branch_k<<<174, 256, 0, stream>>>(PB + 1 * BRS, cbw, cbb, xpbw, dtbw, dtbb, Ablog, Dbv);
  pack_branch_k<<<174, 256, 0, stream>>>(PB + 2 * BRS, csw, csb, xpsw, dtsw, dtsb, Aslog, Dsv);

  // 1) conv1 (through the x_flat shuffle) -> (b,n,256); then LayerNorm in place
  conv3x3_k<<<dim3(2, 128), 256, 0, stream>>>(x, W1T, p1b, XCT, 0);
  layernorm_k<<<4096, 256, 0, stream>>>(XCT, nw, nb);

  // 2) Q,K,V projections
  gemm(XCT, qw, qb, Qb, 4096, 256, 256, 256, 1, 256, 1, 256, 1, 1,
       0, 0, 0, 0, 0, 0, 0, 1.f, 0);
  gemm(XCT, kw, kb, Kb, 4096, 256, 256, 256, 1, 256, 1, 256, 1, 1,
       0, 0, 0, 0, 0, 0, 0, 1.f, 0);
  gemm(XCT, vw, vb, Vb, 4096, 256, 256, 256, 1, 256, 1, 256, 1, 1,
       0, 0, 0, 0, 0, 0, 0, 1.f, 0);

  // 3) scores = QK^T / sqrt(128), batched over (b,h)
  gemm(Qb, Kb, nullptr, SC, 1024, 1024, 128, 256, 1, 256, 1, 1024, 8, 2,
       262144, 128, 262144, 128, 2097152, 1048576, 0, 0.08838834764831845f, 0);
  softmax_k<<<8192, 256, 0, stream>>>(SC);

  // 4) att = probs @ V (B as [n=d, k] with b_sn=1,b_sk=256)
  gemm(SC, Vb, nullptr, ATT, 1024, 128, 1024, 1024, 1, 1, 256, 256, 8, 2,
       2097152, 1048576, 262144, 128, 262144, 128, 0, 1.f, 0);

  // 5) output projection -> HS (this is mamba's hs via the reshape trick)
  gemm(ATT, ow, ob, HS, 4096, 256, 256, 256, 1, 256, 1, 256, 1, 1,
       0, 0, 0, 0, 0, 0, 0, 1.f, 0);

  // 6) xz[b,l,e] = sum_d hs[b,l,d]*in_w[e,d]; hs read col-major (reshape trick)
  gemm(HS, inw, nullptr, XZ, 1024, 1024, 256, 1, 1024, 256, 1, 1024, 4, 1,
       262144, 0, 0, 0, 1048576, 0, 0, 1.f, 0);

  // 7) causal conv1d + silu (3 branches)
  cconv_k<<<24576, 256, 0, stream>>>(XZ, PB, XMC);

  // 8) x_dbl = xm @ xpw^T  (N=48)
  gemm(XMC, PB + 2560, nullptr, XDBL, 4096, 48, 512, 512, 1, 512, 1, 48, 3, 1,
       2097152, 0, BRS, 0, 196608, 0, 0, 1.f, 0);

  // 9) dt = softplus(x_dbl[:,:16] @ dtw^T + dtb)
  gemm(XDBL, PB + 27136, PB + 35328, DT, 4096, 512, 16, 48, 1, 16, 1, 512, 3, 1,
       196608, 0, BRS, 0, 2097152, 0, BRS, 1.f, 2);

  // 10) selective scan (3 branches), y includes +D*u and *silu(z)
  scan_k<<<dim3(512, 3), 64, 0, stream>>>(XMC, DT, XDBL, XZ, PB, Y);

  // 11) comb = y_fwd + rev(y_bwd) + unshuffle(y_s)
  combine_k<<<8192, 256, 0, stream>>>(Y, COMB);

  // 12) mamba out projection -> (b,l,256)
  gemm(COMB, outw, nullptr, XMB, 4096, 256, 512, 512, 1, 512, 1, 256, 1, 1,
       0, 0, 0, 0, 0, 0, 0, 1.f, 0);

  // 13) conv1 again (NHWC input) + relu
  conv3x3_k<<<dim3(2, 128), 256, 0, stream>>>(XMB, W1T, p1b, XM2, 1);

  // 14) 1x1 conv (proj2) + relu
  gemm(XM2, p2w, p2b, XP, 4096, 256, 256, 256, 1, 256, 1, 256, 1, 1,
       0, 0, 0, 0, 0, 0, 0, 1.f, 1);

  // 15) fc1
  gemm(XP, fc1w, fc1b, XF, 4096, 256, 256, 256, 1, 256, 1, 256, 1, 1,
       0, 0, 0, 0, 0, 0, 0, 1.f, 0);

  // 16) depthwise 3x3 + residual -> NCHW output
  dw_k<<<128, 256, 0, stream>>>(XF, dww, dwb, x, out);
}

// Round 2
// 1375.157 us; speedup vs baseline: 1.4696x; 1.4696x over previous
//
#include <hip/hip_runtime.h>

// ---------------------------------------------------------------------------
// Att_MambaLayer: full-graph f32 implementation, chunked selective scan.
// Shapes: B=4, C=256, H=W=32, N=l=1024, NH=2, dh=128, DI=512, DS=16, DTR=16.
// ---------------------------------------------------------------------------

#define LOG2E 1.4426950408889634f
#define NCH 8          // scan chunks
#define LCH 128        // chunk length

// ---- workspace layout (f32 element offsets) -------------------------------
static const long OFF_W1T  = 0;         // 589,824 (conv1 weights^T)
static const long OFF_PB   = 589824;    // 3 * 44,544 packed branch params
static const long BRS      = 44544;
static const long OFF_XCT  = 750000;    // (b,n,256) conv1-out/LN; scan: SE
static const long OFF_R1   = 1800000;   // 12.6M phase-reuse region
static const long OFF_HS   = 14400000;  // (b,n,256) o-proj out; scan: PC
static const long OFF_XZ   = 15450000;  // (b,l,1024)
static const long OFF_XDBL = 19650000;  // [3][4096][48]
static const long OFF_Y    = 20250000;  // [12][1024][512]; attn: WQKV pack
static const long OFF_COMB = 26550000;  // (b,l,512); scan: SI
// R1 tenants: attn  : QKV(+0, 3.1M) SC(+3145728, 8.39M) ATT(+11534336, 1M)
//             mamba : XMC(+0, 6.29M) DT(+6291456, 6.29M)
//             tail  : XMB(+0) XM2(+1048576) XP(+2097152) XF(+3145728)

// ---------------------------------------------------------------------------
__device__ __forceinline__ float block_reduce256(float v, int op) {
  #pragma unroll
  for (int m = 32; m; m >>= 1) {
    float o = __shfl_xor(v, m);
    v = op ? fmaxf(v, o) : v + o;
  }
  __shared__ float sm[4];
  if ((threadIdx.x & 63) == 0) sm[threadIdx.x >> 6] = v;
  __syncthreads();
  v = op ? fmaxf(fmaxf(sm[0], sm[1]), fmaxf(sm[2], sm[3]))
         : (sm[0] + sm[1] + sm[2] + sm[3]);
  __syncthreads();
  return v;
}

// ---- param packing --------------------------------------------------------
__global__ __launch_bounds__(256) void pack_w1t_k(const float* __restrict__ w,
                                                  float* __restrict__ w1t) {
  int j = blockIdx.x, co = threadIdx.x;          // j = ci*9+kh*3+kw
  w1t[j * 256 + co] = w[co * 2304 + j];
}

__global__ __launch_bounds__(256) void pack_branch_k(
    float* __restrict__ dst, const float* __restrict__ cw,
    const float* __restrict__ cb, const float* __restrict__ xpw,
    const float* __restrict__ dtw, const float* __restrict__ dtb,
    const float* __restrict__ Alog, const float* __restrict__ Dv) {
  int t = blockIdx.x * 256 + threadIdx.x;        // < 44,544
  if (t < 2048) dst[t] = cw[t];
  else if (t < 2560) dst[t] = cb[t - 2048];
  else if (t < 27136) dst[t] = xpw[t - 2560];
  else if (t < 35328) dst[t] = dtw[t - 27136];
  else if (t < 35840) dst[t] = dtb[t - 35328];
  else if (t < 44032) dst[t] = -expf(Alog[t - 35840]) * LOG2E;
  else if (t < 44544) dst[t] = Dv[t - 44032];
}

// pack q/k/v weights+biases into [768][256] + [768]
__global__ __launch_bounds__(256) void pack_qkv_k(
    const float* __restrict__ qw, const float* __restrict__ kw,
    const float* __restrict__ vw, const float* __restrict__ qb,
    const float* __restrict__ kb, const float* __restrict__ vb,
    float* __restrict__ dst) {
  int t = blockIdx.x * 256 + threadIdx.x;        // < 197,376
  if (t < 65536) dst[t] = qw[t];
  else if (t < 131072) dst[t] = kw[t - 65536];
  else if (t < 196608) dst[t] = vw[t - 131072];
  else if (t < 196864) dst[t] = qb[t - 196608];
  else if (t < 197120) dst[t] = kb[t - 196864];
  else if (t < 197376) dst[t] = vb[t - 197120];
}

// ---- 3x3 conv (C=256->256, pad 1), NHWC output (b,n,co) -------------------
__global__ __launch_bounds__(256) void conv3x3_k(
    const float* __restrict__ in, const float* __restrict__ w1t,
    const float* __restrict__ bias, float* __restrict__ out, int mode) {
  __shared__ float patch[3 * 256 * 20];
  int w0 = blockIdx.x * 16;
  int bh = blockIdx.y;
  int b = bh >> 5, h0 = bh & 31;
  int tid = threadIdx.x;

  if (mode == 0) {
    for (int t = tid; t < 3 * 256 * 18; t += 256) {
      int wi = t % 18; int r = t / 18; int ci = r & 255; int kh = r >> 8;
      int hh = h0 + kh - 1, wg = w0 + wi - 1;
      float v = 0.f;
      if ((unsigned)hh < 32u && (unsigned)wg < 32u) {
        int idx = ci * 32 + hh;                  // x_flat shuffle
        v = in[((long)b << 18) + ((long)(idx & 255) << 10) + ((idx >> 8) << 5) + wg];
      }
      patch[(kh * 256 + ci) * 20 + wi] = v;
    }
  } else {
    for (int t = tid; t < 3 * 256 * 18; t += 256) {
      int ci = t & 255; int r = t >> 8; int wi = r % 18; int kh = r / 18;
      int hh = h0 + kh - 1, wg = w0 + wi - 1;
      float v = 0.f;
      if ((unsigned)hh < 32u && (unsigned)wg < 32u)
        v = in[(((long)b << 10) + (hh << 5) + wg) * 256 + ci];
      patch[(kh * 256 + ci) * 20 + wi] = v;
    }
  }
  __syncthreads();

  float acc[16] = {};
  int co = tid;
  for (int ci = 0; ci < 256; ++ci) {
    #pragma unroll
    for (int kh = 0; kh < 3; ++kh) {
      const float* pr = &patch[(kh * 256 + ci) * 20];
      float p[20];
      #pragma unroll
      for (int q = 0; q < 5; ++q) {
        float4 f = ((const float4*)pr)[q];
        p[q * 4] = f.x; p[q * 4 + 1] = f.y; p[q * 4 + 2] = f.z; p[q * 4 + 3] = f.w;
      }
      const float* wp = &w1t[(ci * 9 + kh * 3) * 256 + co];
      float wv0 = wp[0], wv1 = wp[256], wv2 = wp[512];
      #pragma unroll
      for (int w = 0; w < 16; ++w)
        acc[w] = fmaf(p[w], wv0, fmaf(p[w + 1], wv1, fmaf(p[w + 2], wv2, acc[w])));
    }
  }
  float bb = bias[co];
  #pragma unroll
  for (int w = 0; w < 16; ++w) {
    float v = acc[w] + bb;
    if (mode) v = fmaxf(v, 0.f);
    out[(((long)b << 10) + (h0 << 5) + (w0 + w)) * 256 + co] = v;
  }
}

// ---- LayerNorm over channel dim (rows of 256), in place -------------------
__global__ __launch_bounds__(256) void layernorm_k(float* __restrict__ x,
                                                   const float* __restrict__ w,
                                                   const float* __restrict__ b) {
  float* p = x + (long)blockIdx.x * 256;
  float v = p[threadIdx.x];
  float mean = block_reduce256(v, 0) * (1.f / 256.f);
  float d = v - mean;
  float var = block_reduce256(d * d, 0) * (1.f / 256.f);
  p[threadIdx.x] = d * rsqrtf(var + 1e-5f) * w[threadIdx.x] + b[threadIdx.x];
}

// ---- softmax over rows of 1024 --------------------------------------------
__global__ __launch_bounds__(256) void softmax_k(float* __restrict__ S) {
  float* p = S + (long)blockIdx.x * 1024;
  float4 v = ((float4*)p)[threadIdx.x];
  float m = fmaxf(fmaxf(v.x, v.y), fmaxf(v.z, v.w));
  m = block_reduce256(m, 1);
  v.x = expf(v.x - m); v.y = expf(v.y - m);
  v.z = expf(v.z - m); v.w = expf(v.w - m);
  float s = block_reduce256(v.x + v.y + v.z + v.w, 0);
  float inv = 1.f / s;
  v.x *= inv; v.y *= inv; v.z *= inv; v.w *= inv;
  ((float4*)p)[threadIdx.x] = v;
}

// ---- generic strided batched GEMM -----------------------------------------
__global__ __launch_bounds__(256) void gemm_k(
    const float* __restrict__ A, const float* __restrict__ B,
    const float* __restrict__ bias, float* __restrict__ Out,
    int M, int N, int K,
    int a_sm, int a_sk, int b_sn, int b_sk, int o_sm,
    int zdiv, long a_zb, long a_zh, long b_zb, long b_zh, long o_zb, long o_zh,
    long bias_zb, float alpha, int act) {
  int z = blockIdx.z, zb = z / zdiv, zh = z % zdiv;
  const float* Ab = A + zb * a_zb + zh * a_zh;
  const float* Bb = B + zb * b_zb + zh * b_zh;
  const float* biasb = bias ? (bias + zb * bias_zb) : nullptr;
  float* Ob = Out + zb * o_zb + zh * o_zh;
  __shared__ float As[16][68];
  __shared__ float Bs[16][68];
  int m0 = blockIdx.x * 64, n0 = blockIdx.y * 64;
  int tid = threadIdx.x;
  int tm = tid >> 4, tn = tid & 15;
  float acc[4][4] = {};
  for (int k0 = 0; k0 < K; k0 += 16) {
    #pragma unroll
    for (int it = 0; it < 4; ++it) {
      int i = tid + it * 256;
      if (a_sk == 1) {
        int rr = i >> 4, kk = i & 15;
        int gm = m0 + rr, gk = k0 + kk;
        float av = 0.f;
        if (gm < M && gk < K) av = Ab[(long)gm * a_sm + gk];
        As[kk][rr] = av;
      } else {
        int rr = i & 63, kk = i >> 6;
        int gm = m0 + rr, gk = k0 + kk;
        float av = 0.f;
        if (gm < M && gk < K) av = Ab[(long)gm * a_sm + (long)gk * a_sk];
        As[kk][rr] = av;
      }
      if (b_sk == 1) {
        int rr = i >> 4, kk = i & 15;
        int gn = n0 + rr, gk = k0 + kk;
        float bv = 0.f;
        if (gn < N && gk < K) bv = Bb[(long)gn * b_sn + gk];
        Bs[kk][rr] = bv;
      } else {
        int rr = i & 63, kk = i >> 6;
        int gn = n0 + rr, gk = k0 + kk;
        float bv = 0.f;
        if (gn < N && gk < K) bv = Bb[(long)gn * b_sn + (long)gk * b_sk];
        Bs[kk][rr] = bv;
      }
    }
    __syncthreads();
    #pragma unroll
    for (int kk = 0; kk < 16; ++kk) {
      float ar[4], br_[4];
      #pragma unroll
      for (int q = 0; q < 4; ++q) ar[q] = As[kk][tm * 4 + q];
      #pragma unroll
      for (int q = 0; q < 4; ++q) br_[q] = Bs[kk][tn * 4 + q];
      #pragma unroll
      for (int qi = 0; qi < 4; ++qi)
        #pragma unroll
        for (int qj = 0; qj < 4; ++qj)
          acc[qi][qj] = fmaf(ar[qi], br_[qj], acc[qi][qj]);
    }
    __syncthreads();
  }
  #pragma unroll
  for (int qi = 0; qi < 4; ++qi) {
    int gm = m0 + tm * 4 + qi;
    if (gm >= M) continue;
    #pragma unroll
    for (int qj = 0; qj < 4; ++qj) {
      int gn = n0 + tn * 4 + qj;
      if (gn >= N) continue;
      float v = acc[qi][qj] * alpha + (biasb ? biasb[gn] : 0.f);
      if (act == 1) v = fmaxf(v, 0.f);
      else if (act == 2) v = (v > 30.f) ? v : log1pf(expf(v));
      Ob[(long)gm * o_sm + gn] = v;
    }
  }
}

// ---- branch sequence index map --------------------------------------------
__device__ __forceinline__ int brmap(int br, int j) {
  if (br == 0) return j;
  if (br == 1) return 1023 - j;
  return ((j & 15) << 6) | (j >> 4);   // NSL=16 shuffle
}

// ---- causal depthwise conv1d (k=4) + silu, all 3 branches -----------------
__global__ __launch_bounds__(256) void cconv_k(const float* __restrict__ xz,
                                               const float* __restrict__ pk,
                                               float* __restrict__ xmc) {
  long t = (long)blockIdx.x * 256 + threadIdx.x;   // < 6,291,456
  int d = (int)(t & 511);
  long r = t >> 9;
  int j = (int)(r & 1023);
  int bb = (int)(r >> 10);
  int b = bb & 3, br = bb >> 2;
  const float* pb = pk + (long)br * BRS;
  float acc = pb[2048 + d];                        // cb
  #pragma unroll
  for (int tap = 0; tap < 4; ++tap) {
    int jj = j - 3 + tap;
    if (jj >= 0) {
      int l = brmap(br, jj);
      acc = fmaf(xz[(((long)b << 10) + l) * 1024 + d], pb[d * 4 + tap], acc);
    }
  }
  float sig = 1.f / (1.f + expf(-acc));
  xmc[t] = acc * sig;
}

// ---- chunked selective scan -----------------------------------------------
// blocks: (384, NCH); 256 thr = 16 groups of 16 lanes; group g -> row
// r = blockIdx.x*16+g; br=r>>11, b=(r>>9)&3, d=r&511 (16 consecutive d/block
// so the 4B broadcast dt/xmc loads use full cachelines).
// state buffers layout: [br*4+b][chunk][d][n]

// pass A: local scan with s_in=0; store end state + dA product
__global__ __launch_bounds__(256) void scanA_k(
    const float* __restrict__ xmc, const float* __restrict__ dt,
    const float* __restrict__ xdbl, const float* __restrict__ pk,
    float* __restrict__ SE, float* __restrict__ PC) {
  int g = threadIdx.x >> 4, n = threadIdx.x & 15;
  int r = blockIdx.x * 16 + g;
  int br = r >> 11, b = (r >> 9) & 3, d = r & 511;
  int c = blockIdx.y;
  const float* pb = pk + (long)br * BRS;
  float Aln = pb[35840 + d * 16 + n];
  long mbase = ((long)(br * 4 + b)) << 19;
  long xdb = (long)br * 196608 + (long)b * 49152;
  float s = 0.f, P = 1.f;
  int j0 = c * LCH;
  for (int j = j0; j < j0 + LCH; ++j) {
    long o = mbase + ((long)j << 9) + d;
    float delta = dt[o];
    float u = xmc[o];
    long xo = xdb + (long)j * 48;
    float Bv = xdbl[xo + 16 + n];
    float dA = exp2f(delta * Aln);
    s = fmaf(dA, s, delta * u * Bv);
    P *= dA;
  }
  long si = ((((long)(br * 4 + b)) * NCH + c) * 512 + d) * 16 + n;
  SE[si] = s;
  PC[si] = P;
}

// pass B: propagate chunk incoming states (sequential over NCH)
__global__ __launch_bounds__(256) void scanB_k(const float* __restrict__ SE,
                                               const float* __restrict__ PC,
                                               float* __restrict__ SI) {
  long t = (long)blockIdx.x * 256 + threadIdx.x;   // < 98,304
  int n = (int)(t & 15);
  int d = (int)((t >> 4) & 511);
  int bb = (int)(t >> 13);                         // br*4+b
  float run = 0.f;
  for (int c = 0; c < NCH; ++c) {
    long si = (((long)bb * NCH + c) * 512 + d) * 16 + n;
    SI[si] = run;
    run = fmaf(PC[si], run, SE[si]);
  }
}

// pass C: re-scan with correct incoming state, emit y
__global__ __launch_bounds__(256) void scanC_k(
    const float* __restrict__ xmc, const float* __restrict__ dt,
    const float* __restrict__ xdbl, const float* __restrict__ xz,
    const float* __restrict__ pk, const float* __restrict__ SI,
    float* __restrict__ y) {
  int g = threadIdx.x >> 4, n = threadIdx.x & 15;
  int r = blockIdx.x * 16 + g;
  int br = r >> 11, b = (r >> 9) & 3, d = r & 511;
  int c = blockIdx.y;
  const float* pb = pk + (long)br * BRS;
  float Aln = pb[35840 + d * 16 + n];
  float Dv = pb[44032 + d];
  long mbase = ((long)(br * 4 + b)) << 19;
  long xdb = (long)br * 196608 + (long)b * 49152;
  long xzb = ((long)b << 20) + 512 + d;
  long si = ((((long)(br * 4 + b)) * NCH + c) * 512 + d) * 16 + n;
  float s = SI[si];
  int j0 = c * LCH;
  for (int j = j0; j < j0 + LCH; ++j) {
    long o = mbase + ((long)j << 9) + d;
    float delta = dt[o];
    float u = xmc[o];
    long xo = xdb + (long)j * 48;
    float Bv = xdbl[xo + 16 + n];
    float Cv = xdbl[xo + 32 + n];
    float dA = exp2f(delta * Aln);
    s = fmaf(dA, s, delta * u * Bv);
    float p = s * Cv;
    p += __shfl_xor(p, 1);
    p += __shfl_xor(p, 2);
    p += __shfl_xor(p, 4);
    p += __shfl_xor(p, 8);
    if (n == 0) {
      int l = brmap(br, j);
      float zv = xz[xzb + ((long)l << 10)];
      float sig = 1.f / (1.f + expf(-zv));
      y[o] = (p + Dv * u) * (zv * sig);
    }
  }
}

// ---- combine the 3 branch outputs into comb (b,l,512) ---------------------
__global__ __launch_bounds__(256) void combine_k(const float* __restrict__ y,
                                                 float* __restrict__ comb) {
  long t = (long)blockIdx.x * 256 + threadIdx.x;   // < 2,097,152
  int d = (int)(t & 511);
  long r = t >> 9;
  int l = (int)(r & 1023);
  int b = (int)(r >> 10);
  int j2 = ((l & 63) << 4) | (l >> 6);             // inverse NSL shuffle
  float v = y[(((long)b << 10) + l) * 512 + d]
          + y[(((long)(4 + b) << 10) + (1023 - l)) * 512 + d]
          + y[(((long)(8 + b) << 10) + j2) * 512 + d];
  comb[t] = v;
}

// ---- depthwise 3x3 conv + residual add, writes NCHW output ----------------
__global__ __launch_bounds__(256) void dw_k(const float* __restrict__ xf,
                                            const float* __restrict__ dww,
                                            const float* __restrict__ dwb,
                                            const float* __restrict__ x,
                                            float* __restrict__ out) {
  int t = blockIdx.x;                              // (b,h): 128
  int b = t >> 5, h = t & 31;
  int c = threadIdx.x;
  float wv[9];
  #pragma unroll
  for (int k = 0; k < 9; ++k) wv[k] = dww[c * 9 + k];
  float bb = dwb[c];
  for (int w = 0; w < 32; ++w) {
    float acc = bb;
    #pragma unroll
    for (int kh = 0; kh < 3; ++kh) {
      int hh = h + kh - 1;
      if ((unsigned)hh >= 32u) continue;
      #pragma unroll
      for (int kw = 0; kw < 3; ++kw) {
        int ww = w + kw - 1;
        if ((unsigned)ww >= 32u) continue;
        acc = fmaf(xf[(((long)b << 10) + (hh << 5) + ww) * 256 + c],
                   wv[kh * 3 + kw], acc);
      }
    }
    long oi = (((long)b * 256 + c) * 32 + h) * 32 + w;
    out[oi] = acc + x[oi];
  }
}

// ---------------------------------------------------------------------------
extern "C" void kernel_launch(void* const* d_in, const int* in_sizes, int n_in,
                              void* d_out, int out_size, void* d_ws, size_t ws_size,
                              hipStream_t stream) {
  (void)in_sizes; (void)n_in; (void)out_size; (void)ws_size;
  const float* x    = (const float*)d_in[0];
  const float* p1w  = (const float*)d_in[1];
  const float* p1b  = (const float*)d_in[2];
  const float* p2w  = (const float*)d_in[3];
  const float* p2b  = (const float*)d_in[4];
  const float* nw   = (const float*)d_in[5];
  const float* nb   = (const float*)d_in[6];
  const float* qw   = (const float*)d_in[7];
  const float* qb   = (const float*)d_in[8];
  const float* kw   = (const float*)d_in[9];
  const float* kb   = (const float*)d_in[10];
  const float* vw   = (const float*)d_in[11];
  const float* vb   = (const float*)d_in[12];
  const float* ow   = (const float*)d_in[13];
  const float* ob   = (const float*)d_in[14];
  const float* fc1w = (const float*)d_in[15];
  const float* fc1b = (const float*)d_in[16];
  const float* dww  = (const float*)d_in[17];
  const float* dwb  = (const float*)d_in[18];
  const float* inw  = (const float*)d_in[19];
  const float* cw   = (const float*)d_in[20];
  const float* cb   = (const float*)d_in[21];
  const float* cbw  = (const float*)d_in[22];
  const float* cbb  = (const float*)d_in[23];
  const float* csw  = (const float*)d_in[24];
  const float* csb  = (const float*)d_in[25];
  const float* xpw  = (const float*)d_in[26];
  const float* xpbw = (const float*)d_in[27];
  const float* xpsw = (const float*)d_in[28];
  const float* dtw  = (const float*)d_in[29];
  const float* dtb  = (const float*)d_in[30];
  const float* dtbw = (const float*)d_in[31];
  const float* dtbb = (const float*)d_in[32];
  const float* dtsw = (const float*)d_in[33];
  const float* dtsb = (const float*)d_in[34];
  const float* Alog = (const float*)d_in[35];
  const float* Ablog= (const float*)d_in[36];
  const float* Aslog= (const float*)d_in[37];
  const float* Dv   = (const float*)d_in[38];
  const float* Dbv  = (const float*)d_in[39];
  const float* Dsv  = (const float*)d_in[40];
  const float* outw = (const float*)d_in[41];
  float* out = (float*)d_out;

  float* ws = (float*)d_ws;
  float* W1T = ws + OFF_W1T;
  float* PB  = ws + OFF_PB;
  float* XCT = ws + OFF_XCT;
  float* R1  = ws + OFF_R1;
  float* QKV = R1;                         // attn phase
  float* SC  = R1 + 3145728;
  float* ATT = R1 + 11534336;
  float* XMC = R1;                         // mamba phase
  float* DT  = R1 + 6291456;
  float* XMB = R1;                         // tail phase
  float* XM2 = R1 + 1048576;
  float* XP  = R1 + 2097152;
  float* XF  = R1 + 3145728;
  float* HS  = ws + OFF_HS;
  float* XZ  = ws + OFF_XZ;
  float* XDBL= ws + OFF_XDBL;
  float* Y   = ws + OFF_Y;
  float* WQKV= ws + OFF_Y;                 // attn phase only (Y dead then)
  float* COMB= ws + OFF_COMB;
  float* SE  = ws + OFF_XCT;               // scan phase (XCT dead)
  float* PC  = ws + OFF_HS;                // scan phase (HS dead)
  float* SI  = ws + OFF_COMB;              // scan phase (COMB written later)

  auto gemm = [&](const float* A, const float* Bm, const float* bias, float* Out,
                  int M, int N, int K,
                  int a_sm, int a_sk, int b_sn, int b_sk, int o_sm,
                  int nz, int zdiv,
                  long a_zb, long a_zh, long b_zb, long b_zh, long o_zb, long o_zh,
                  long bias_zb, float alpha, int act) {
    dim3 g((M + 63) / 64, (N + 63) / 64, nz);
    gemm_k<<<g, 256, 0, stream>>>(A, Bm, bias, Out, M, N, K,
                                  a_sm, a_sk, b_sn, b_sk, o_sm, zdiv,
                                  a_zb, a_zh, b_zb, b_zh, o_zb, o_zh, bias_zb,
                                  alpha, act);
  };

  // 0) pack params
  pack_w1t_k<<<2304, 256, 0, stream>>>(p1w, W1T);
  pack_branch_k<<<174, 256, 0, stream>>>(PB + 0 * BRS, cw, cb, xpw, dtw, dtb, Alog, Dv);
  pack_branch_k<<<174, 256, 0, stream>>>(PB + 1 * BRS, cbw, cbb, xpbw, dtbw, dtbb, Ablog, Dbv);
  pack_branch_k<<<174, 256, 0, stream>>>(PB + 2 * BRS, csw, csb, xpsw, dtsw, dtsb, Aslog, Dsv);
  pack_qkv_k<<<771, 256, 0, stream>>>(qw, kw, vw, qb, kb, vb, WQKV);

  // 1) conv1 (through x_flat shuffle) -> (b,n,256); LayerNorm in place
  conv3x3_k<<<dim3(2, 128), 256, 0, stream>>>(x, W1T, p1b, XCT, 0);
  layernorm_k<<<4096, 256, 0, stream>>>(XCT, nw, nb);

  // 2) fused QKV projection -> QKV[(b,n)][768]
  gemm(XCT, WQKV, WQKV + 196608, QKV, 4096, 768, 256, 256, 1, 256, 1, 768, 1, 1,
       0, 0, 0, 0, 0, 0, 0, 1.f, 0);

  // 3) scores = QK^T / sqrt(128), batched over (b,h)
  gemm(QKV, QKV + 256, nullptr, SC, 1024, 1024, 128, 768, 1, 768, 1, 1024, 8, 2,
       786432, 128, 786432, 128, 2097152, 1048576, 0, 0.08838834764831845f, 0);
  softmax_k<<<8192, 256, 0, stream>>>(SC);

  // 4) att = probs @ V -> ATT (b,n,256)
  gemm(SC, QKV + 512, nullptr, ATT, 1024, 128, 1024, 1024, 1, 1, 768, 256, 8, 2,
       2097152, 1048576, 786432, 128, 262144, 128, 0, 1.f, 0);

  // 5) output projection -> HS (mamba's hs via reshape trick)
  gemm(ATT, ow, ob, HS, 4096, 256, 256, 256, 1, 256, 1, 256, 1, 1,
       0, 0, 0, 0, 0, 0, 0, 1.f, 0);

  // 6) xz[b,l,e] = sum_d hs[b,l,d]*in_w[e,d]
  gemm(HS, inw, nullptr, XZ, 1024, 1024, 256, 1, 1024, 256, 1, 1024, 4, 1,
       262144, 0, 0, 0, 1048576, 0, 0, 1.f, 0);

  // 7) causal conv1d + silu (3 branches)
  cconv_k<<<24576, 256, 0, stream>>>(XZ, PB, XMC);

  // 8) x_dbl = xm @ xpw^T  (N=48)
  gemm(XMC, PB + 2560, nullptr, XDBL, 4096, 48, 512, 512, 1, 512, 1, 48, 3, 1,
       2097152, 0, BRS, 0, 196608, 0, 0, 1.f, 0);

  // 9) dt = softplus(x_dbl[:,:16] @ dtw^T + dtb)
  gemm(XDBL, PB + 27136, PB + 35328, DT, 4096, 512, 16, 48, 1, 16, 1, 512, 3, 1,
       196608, 0, BRS, 0, 2097152, 0, BRS, 1.f, 2);

  // 10) chunked selective scan (3 branches)
  scanA_k<<<dim3(384, NCH), 256, 0, stream>>>(XMC, DT, XDBL, PB, SE, PC);
  scanB_k<<<384, 256, 0, stream>>>(SE, PC, SI);
  scanC_k<<<dim3(384, NCH), 256, 0, stream>>>(XMC, DT, XDBL, XZ, PB, SI, Y);

  // 11) comb = y_fwd + rev(y_bwd) + unshuffle(y_s)
  combine_k<<<8192, 256, 0, stream>>>(Y, COMB);

  // 12) mamba out projection -> (b,l,256)
  gemm(COMB, outw, nullptr, XMB, 4096, 256, 512, 512, 1, 512, 1, 256, 1, 1,
       0, 0, 0, 0, 0, 0, 0, 1.f, 0);

  // 13) conv1 again (NHWC input) + relu
  conv3x3_k<<<dim3(2, 128), 256, 0, stream>>>(XMB, W1T, p1b, XM2, 1);

  // 14) 1x1 conv (proj2) + relu
  gemm(XM2, p2w, p2b, XP, 4096, 256, 256, 256, 1, 256, 1, 256, 1, 1,
       0, 0, 0, 0, 0, 0, 0, 1.f, 1);

  // 15) fc1
  gemm(XP, fc1w, fc1b, XF, 4096, 256, 256, 256, 1, 256, 1, 256, 1, 1,
       0, 0, 0, 0, 0, 0, 0, 1.f, 0);

  // 16) depthwise 3x3 + residual -> NCHW output
  dw_k<<<128, 256, 0, stream>>>(XF, dww, dwb, x, out);
}

// Round 3
// 985.791 us; speedup vs baseline: 2.0501x; 1.3950x over previous
//
#include <hip/hip_runtime.h>

// ---------------------------------------------------------------------------
// Att_MambaLayer: bf16-MFMA GEMMs + chunked selective scan (f32).
// B=4, C=256, H=W=32, N=l=1024, NH=2, dh=128, DI=512, DS=16, DTR=16.
// ---------------------------------------------------------------------------

#define LOG2E 1.4426950408889634f
#define NCH 8
#define LCH 128

typedef unsigned short u16;
typedef unsigned int u32;
typedef __attribute__((ext_vector_type(8))) short bf16x8;
typedef __attribute__((ext_vector_type(4))) float f32x4;

__device__ __forceinline__ u16 f2b(float f) {
  u32 u = __builtin_bit_cast(u32, f);
  u32 r = (u + 0x7fffu + ((u >> 16) & 1u)) >> 16;
  return (u16)r;
}
__device__ __forceinline__ float b2f(u16 h) {
  u32 u = ((u32)h) << 16;
  return __builtin_bit_cast(float, u);
}

// ---- workspace layout (f32 element offsets) -------------------------------
static const long BRS = 44544;
// W1T 0..589824 | PB 589824..723456 | WB(u16) 723456.. (786432 u16)
// QBIAS 1116672..1117440 | R 1200000
// attn:  XCT R+0 | XCTB(u16) R+1.1M | QKVB(u16) R+1.7M | VT(u16) R+3.3M
//        SC R+3.9M | P(u16) R+12.3M | ATTB(u16) R+16.5M | HS R+17.1M
//        XATTB(u16) R+18.2M
// scan:  Y(u16) R+18.8M | XZ R+22.0M
// mamba: XMC R+0 | DT R+6.3M | XDBL R+12.6M | SE R+13.2M | PC R+14.0M | SI R+14.8M
// tail:  COMBB(u16) R+0 | XMB R+0.6M | XM2B(u16) R+1.7M | XPB(u16) R+2.3M | XF R+2.9M

// ---------------------------------------------------------------------------
__device__ __forceinline__ float block_reduce256(float v, int op) {
  #pragma unroll
  for (int m = 32; m; m >>= 1) {
    float o = __shfl_xor(v, m);
    v = op ? fmaxf(v, o) : v + o;
  }
  __shared__ float sm[4];
  if ((threadIdx.x & 63) == 0) sm[threadIdx.x >> 6] = v;
  __syncthreads();
  v = op ? fmaxf(fmaxf(sm[0], sm[1]), fmaxf(sm[2], sm[3]))
         : (sm[0] + sm[1] + sm[2] + sm[3]);
  __syncthreads();
  return v;
}

// ---- param packing --------------------------------------------------------
__global__ __launch_bounds__(256) void pack_w1t_k(const float* __restrict__ w,
                                                  float* __restrict__ w1t) {
  int j = blockIdx.x, co = threadIdx.x;
  w1t[j * 256 + co] = w[co * 2304 + j];
}

__global__ __launch_bounds__(256) void pack_branch_k(
    float* __restrict__ dst, const float* __restrict__ cw,
    const float* __restrict__ cb, const float* __restrict__ xpw,
    const float* __restrict__ dtw, const float* __restrict__ dtb,
    const float* __restrict__ Alog, const float* __restrict__ Dv) {
  int t = blockIdx.x * 256 + threadIdx.x;
  if (t < 2048) dst[t] = cw[t];
  else if (t < 2560) dst[t] = cb[t - 2048];
  else if (t < 27136) dst[t] = xpw[t - 2560];
  else if (t < 35328) dst[t] = dtw[t - 27136];
  else if (t < 35840) dst[t] = dtb[t - 35328];
  else if (t < 44032) dst[t] = -expf(Alog[t - 35840]) * LOG2E;
  else if (t < 44544) dst[t] = Dv[t - 44032];
}

// pack all bf16 weights + qkv bias concat
__global__ __launch_bounds__(256) void pack_wb_k(
    const float* __restrict__ qw, const float* __restrict__ kw,
    const float* __restrict__ vw, const float* __restrict__ ow,
    const float* __restrict__ inw, const float* __restrict__ outw,
    const float* __restrict__ p2w, const float* __restrict__ fc1w,
    const float* __restrict__ qb, const float* __restrict__ kb,
    const float* __restrict__ vb, u16* __restrict__ WB,
    float* __restrict__ QBIAS) {
  int t = blockIdx.x * 256 + threadIdx.x;   // < 787,200
  if (t < 65536) WB[t] = f2b(qw[t]);
  else if (t < 131072) WB[t] = f2b(kw[t - 65536]);
  else if (t < 196608) WB[t] = f2b(vw[t - 131072]);
  else if (t < 262144) WB[t] = f2b(ow[t - 196608]);
  else if (t < 524288) WB[t] = f2b(inw[t - 262144]);
  else if (t < 655360) WB[t] = f2b(outw[t - 524288]);
  else if (t < 720896) WB[t] = f2b(p2w[t - 655360]);
  else if (t < 786432) WB[t] = f2b(fc1w[t - 720896]);
  else if (t < 787200) {
    int i = t - 786432;
    QBIAS[i] = (i < 256) ? qb[i] : (i < 512 ? kb[i - 256] : vb[i - 512]);
  }
}

// ---- 3x3 conv (C=256->256, pad 1), NHWC output ----------------------------
__global__ __launch_bounds__(256) void conv3x3_k(
    const float* __restrict__ in, const float* __restrict__ w1t,
    const float* __restrict__ bias, float* __restrict__ outF,
    u16* __restrict__ outH, int mode) {
  __shared__ float patch[3 * 256 * 20];
  int w0 = blockIdx.x * 16;
  int bh = blockIdx.y;
  int b = bh >> 5, h0 = bh & 31;
  int tid = threadIdx.x;

  if (mode == 0) {
    for (int t = tid; t < 3 * 256 * 18; t += 256) {
      int wi = t % 18; int r = t / 18; int ci = r & 255; int kh = r >> 8;
      int hh = h0 + kh - 1, wg = w0 + wi - 1;
      float v = 0.f;
      if ((unsigned)hh < 32u && (unsigned)wg < 32u) {
        int idx = ci * 32 + hh;                  // x_flat shuffle
        v = in[((long)b << 18) + ((long)(idx & 255) << 10) + ((idx >> 8) << 5) + wg];
      }
      patch[(kh * 256 + ci) * 20 + wi] = v;
    }
  } else {
    for (int t = tid; t < 3 * 256 * 18; t += 256) {
      int ci = t & 255; int r = t >> 8; int wi = r % 18; int kh = r / 18;
      int hh = h0 + kh - 1, wg = w0 + wi - 1;
      float v = 0.f;
      if ((unsigned)hh < 32u && (unsigned)wg < 32u)
        v = in[(((long)b << 10) + (hh << 5) + wg) * 256 + ci];
      patch[(kh * 256 + ci) * 20 + wi] = v;
    }
  }
  __syncthreads();

  float acc[16] = {};
  int co = tid;
  for (int ci = 0; ci < 256; ++ci) {
    #pragma unroll
    for (int kh = 0; kh < 3; ++kh) {
      const float* pr = &patch[(kh * 256 + ci) * 20];
      float p[20];
      #pragma unroll
      for (int q = 0; q < 5; ++q) {
        float4 f = ((const float4*)pr)[q];
        p[q * 4] = f.x; p[q * 4 + 1] = f.y; p[q * 4 + 2] = f.z; p[q * 4 + 3] = f.w;
      }
      const float* wp = &w1t[(ci * 9 + kh * 3) * 256 + co];
      float wv0 = wp[0], wv1 = wp[256], wv2 = wp[512];
      #pragma unroll
      for (int w = 0; w < 16; ++w)
        acc[w] = fmaf(p[w], wv0, fmaf(p[w + 1], wv1, fmaf(p[w + 2], wv2, acc[w])));
    }
  }
  float bb = bias[co];
  #pragma unroll
  for (int w = 0; w < 16; ++w) {
    float v = acc[w] + bb;
    long idx = (((long)b << 10) + (h0 << 5) + (w0 + w)) * 256 + co;
    if (mode) outH[idx] = f2b(fmaxf(v, 0.f));
    else outF[idx] = v;
  }
}

// ---- LayerNorm rows of 256 -> bf16 ----------------------------------------
__global__ __launch_bounds__(256) void layernorm_k(const float* __restrict__ x,
                                                   const float* __restrict__ w,
                                                   const float* __restrict__ b,
                                                   u16* __restrict__ o) {
  const float* p = x + (long)blockIdx.x * 256;
  float v = p[threadIdx.x];
  float mean = block_reduce256(v, 0) * (1.f / 256.f);
  float d = v - mean;
  float var = block_reduce256(d * d, 0) * (1.f / 256.f);
  o[(long)blockIdx.x * 256 + threadIdx.x] =
      f2b(d * rsqrtf(var + 1e-5f) * w[threadIdx.x] + b[threadIdx.x]);
}

// ---- softmax rows of 1024: f32 in, bf16 out -------------------------------
__global__ __launch_bounds__(256) void softmax_k(const float* __restrict__ S,
                                                 u16* __restrict__ P) {
  const float* p = S + (long)blockIdx.x * 1024;
  u16* q = P + (long)blockIdx.x * 1024;
  float4 v = ((const float4*)p)[threadIdx.x];
  float m = fmaxf(fmaxf(v.x, v.y), fmaxf(v.z, v.w));
  m = block_reduce256(m, 1);
  v.x = expf(v.x - m); v.y = expf(v.y - m);
  v.z = expf(v.z - m); v.w = expf(v.w - m);
  float s = block_reduce256(v.x + v.y + v.z + v.w, 0);
  float inv = 1.f / s;
  u32 lo = (u32)f2b(v.x * inv) | ((u32)f2b(v.y * inv) << 16);
  u32 hi = (u32)f2b(v.z * inv) | ((u32)f2b(v.w * inv) << 16);
  ((uint2*)q)[threadIdx.x] = make_uint2(lo, hi);
}

// ---- bf16 MFMA GEMM: Out = act(alpha * A @ B^T + bias) --------------------
// A [M][K] bf16 row-major (lda), B [N][K] bf16 row-major (ldb).
// M%128==0, N%128==0, K%32==0. Tile 128x128, 4 waves (2x2 quadrants).
__global__ __launch_bounds__(256, 2) void bgemm_k(
    const u16* __restrict__ A, const u16* __restrict__ B,
    const float* __restrict__ bias, float* __restrict__ OutF,
    u16* __restrict__ OutH, int M, int N, int K,
    int lda, int ldb, int ldo, int zdiv,
    long a_zb, long a_zh, long b_zb, long b_zh, long o_zb, long o_zh,
    float alpha, int act) {
  __shared__ u16 ldsA[4][128][8];   // [kh][row][8] : k = kh*8 + i
  __shared__ u16 ldsB[4][128][8];
  int z = blockIdx.z, zb = z / zdiv, zh = z - zb * zdiv;
  const u16* Ab = A + zb * a_zb + zh * a_zh;
  const u16* Bb = B + zb * b_zb + zh * b_zh;
  long ob = zb * o_zb + zh * o_zh;
  int m0 = blockIdx.x * 128, n0 = blockIdx.y * 128;
  int tid = threadIdx.x;
  int lane = tid & 63, wv = tid >> 6;
  int wr = wv >> 1, wc = wv & 1;
  int r1 = tid & 127, h1 = tid >> 7;          // slots t and t+256
  int r2 = r1, h2 = h1 + 2;
  const u16* a1 = Ab + (long)(m0 + r1) * lda + h1 * 8;
  const u16* a2 = Ab + (long)(m0 + r2) * lda + h2 * 8;
  const u16* b1 = Bb + (long)(n0 + r1) * ldb + h1 * 8;
  const u16* b2 = Bb + (long)(n0 + r2) * ldb + h2 * 8;

  f32x4 acc[4][4];
  #pragma unroll
  for (int i = 0; i < 4; ++i)
    #pragma unroll
    for (int j = 0; j < 4; ++j) acc[i][j] = (f32x4){0.f, 0.f, 0.f, 0.f};

  bf16x8 ra1 = *(const bf16x8*)a1;
  bf16x8 ra2 = *(const bf16x8*)a2;
  bf16x8 rb1 = *(const bf16x8*)b1;
  bf16x8 rb2 = *(const bf16x8*)b2;

  int nt = K >> 5;
  int kh = lane >> 4, rlo = lane & 15;
  for (int t = 0; t < nt; ++t) {
    __syncthreads();
    *(bf16x8*)&ldsA[h1][r1][0] = ra1;
    *(bf16x8*)&ldsA[h2][r2][0] = ra2;
    *(bf16x8*)&ldsB[h1][r1][0] = rb1;
    *(bf16x8*)&ldsB[h2][r2][0] = rb2;
    if (t + 1 < nt) {
      int ko = (t + 1) << 5;
      ra1 = *(const bf16x8*)(a1 + ko);
      ra2 = *(const bf16x8*)(a2 + ko);
      rb1 = *(const bf16x8*)(b1 + ko);
      rb2 = *(const bf16x8*)(b2 + ko);
    }
    __syncthreads();
    bf16x8 af[4], bfr[4];
    #pragma unroll
    for (int m = 0; m < 4; ++m)
      af[m] = *(const bf16x8*)&ldsA[kh][wr * 64 + m * 16 + rlo][0];
    #pragma unroll
    for (int n = 0; n < 4; ++n)
      bfr[n] = *(const bf16x8*)&ldsB[kh][wc * 64 + n * 16 + rlo][0];
    #pragma unroll
    for (int m = 0; m < 4; ++m)
      #pragma unroll
      for (int n = 0; n < 4; ++n)
        acc[m][n] = __builtin_amdgcn_mfma_f32_16x16x32_bf16(af[m], bfr[n],
                                                            acc[m][n], 0, 0, 0);
  }
  // epilogue: C/D map col=lane&15, row=(lane>>4)*4+j  [m89]
  int rowb = (lane >> 4) * 4;
  #pragma unroll
  for (int m = 0; m < 4; ++m) {
    #pragma unroll
    for (int n = 0; n < 4; ++n) {
      int gn = n0 + wc * 64 + n * 16 + rlo;
      float bv = bias ? bias[gn] : 0.f;
      #pragma unroll
      for (int j = 0; j < 4; ++j) {
        int gm = m0 + wr * 64 + m * 16 + rowb + j;
        float v = acc[m][n][j] * alpha + bv;
        if (act == 1) v = fmaxf(v, 0.f);
        long oi = ob + (long)gm * ldo + gn;
        if (OutH) OutH[oi] = f2b(v);
        else OutF[oi] = v;
      }
    }
  }
}

// ---- V transpose: VT[bh][d][j] = QKVB[(b*1024+j)*768 + 512 + h*128 + d] ----
__global__ __launch_bounds__(256) void vt_k(const u16* __restrict__ qkv,
                                            u16* __restrict__ vt) {
  int t = blockIdx.x * 256 + threadIdx.x;    // < 1,048,576
  int j = t & 1023, d = (t >> 10) & 127, bh = t >> 17;
  int b = bh >> 1, h = bh & 1;
  vt[t] = qkv[((long)(b * 1024 + j)) * 768 + 512 + h * 128 + d];
}

// ---- x_att permute: XATTB[b][l][dm] = bf16(HS[b*262144 + dm*1024 + l]) ----
__global__ __launch_bounds__(256) void xatt_k(const float* __restrict__ hs,
                                              u16* __restrict__ xa) {
  int t = blockIdx.x * 256 + threadIdx.x;    // < 1,048,576
  int dm = t & 255, l = (t >> 8) & 1023, b = t >> 18;
  xa[t] = f2b(hs[((long)b << 18) + dm * 1024 + l]);
}

// ---- branch sequence index map --------------------------------------------
__device__ __forceinline__ int brmap(int br, int j) {
  if (br == 0) return j;
  if (br == 1) return 1023 - j;
  return ((j & 15) << 6) | (j >> 4);
}

// ---- causal depthwise conv1d (k=4) + silu ---------------------------------
__global__ __launch_bounds__(256) void cconv_k(const float* __restrict__ xz,
                                               const float* __restrict__ pk,
                                               float* __restrict__ xmc) {
  long t = (long)blockIdx.x * 256 + threadIdx.x;   // < 6,291,456
  int d = (int)(t & 511);
  long r = t >> 9;
  int j = (int)(r & 1023);
  int bb = (int)(r >> 10);
  int b = bb & 3, br = bb >> 2;
  const float* pb = pk + (long)br * BRS;
  float acc = pb[2048 + d];
  #pragma unroll
  for (int tap = 0; tap < 4; ++tap) {
    int jj = j - 3 + tap;
    if (jj >= 0) {
      int l = brmap(br, jj);
      acc = fmaf(xz[(((long)b << 10) + l) * 1024 + d], pb[d * 4 + tap], acc);
    }
  }
  float sig = 1.f / (1.f + expf(-acc));
  xmc[t] = acc * sig;
}

// ---- f32 SIMT GEMM (kept for small shapes: x_dbl N=48, dt K=16) -----------
__global__ __launch_bounds__(256) void gemm_k(
    const float* __restrict__ A, const float* __restrict__ B,
    const float* __restrict__ bias, float* __restrict__ Out,
    int M, int N, int K,
    int a_sm, int a_sk, int b_sn, int b_sk, int o_sm,
    int zdiv, long a_zb, long a_zh, long b_zb, long b_zh, long o_zb, long o_zh,
    long bias_zb, float alpha, int act) {
  int z = blockIdx.z, zb = z / zdiv, zh = z % zdiv;
  const float* Ab = A + zb * a_zb + zh * a_zh;
  const float* Bb = B + zb * b_zb + zh * b_zh;
  const float* biasb = bias ? (bias + zb * bias_zb) : nullptr;
  float* Ob = Out + zb * o_zb + zh * o_zh;
  __shared__ float As[16][68];
  __shared__ float Bs[16][68];
  int m0 = blockIdx.x * 64, n0 = blockIdx.y * 64;
  int tid = threadIdx.x;
  int tm = tid >> 4, tn = tid & 15;
  float acc[4][4] = {};
  for (int k0 = 0; k0 < K; k0 += 16) {
    #pragma unroll
    for (int it = 0; it < 4; ++it) {
      int i = tid + it * 256;
      if (a_sk == 1) {
        int rr = i >> 4, kk = i & 15;
        int gm = m0 + rr, gk = k0 + kk;
        float av = 0.f;
        if (gm < M && gk < K) av = Ab[(long)gm * a_sm + gk];
        As[kk][rr] = av;
      } else {
        int rr = i & 63, kk = i >> 6;
        int gm = m0 + rr, gk = k0 + kk;
        float av = 0.f;
        if (gm < M && gk < K) av = Ab[(long)gm * a_sm + (long)gk * a_sk];
        As[kk][rr] = av;
      }
      if (b_sk == 1) {
        int rr = i >> 4, kk = i & 15;
        int gn = n0 + rr, gk = k0 + kk;
        float bv = 0.f;
        if (gn < N && gk < K) bv = Bb[(long)gn * b_sn + gk];
        Bs[kk][rr] = bv;
      } else {
        int rr = i & 63, kk = i >> 6;
        int gn = n0 + rr, gk = k0 + kk;
        float bv = 0.f;
        if (gn < N && gk < K) bv = Bb[(long)gn * b_sn + (long)gk * b_sk];
        Bs[kk][rr] = bv;
      }
    }
    __syncthreads();
    #pragma unroll
    for (int kk = 0; kk < 16; ++kk) {
      float ar[4], br_[4];
      #pragma unroll
      for (int q = 0; q < 4; ++q) ar[q] = As[kk][tm * 4 + q];
      #pragma unroll
      for (int q = 0; q < 4; ++q) br_[q] = Bs[kk][tn * 4 + q];
      #pragma unroll
      for (int qi = 0; qi < 4; ++qi)
        #pragma unroll
        for (int qj = 0; qj < 4; ++qj)
          acc[qi][qj] = fmaf(ar[qi], br_[qj], acc[qi][qj]);
    }
    __syncthreads();
  }
  #pragma unroll
  for (int qi = 0; qi < 4; ++qi) {
    int gm = m0 + tm * 4 + qi;
    if (gm >= M) continue;
    #pragma unroll
    for (int qj = 0; qj < 4; ++qj) {
      int gn = n0 + tn * 4 + qj;
      if (gn >= N) continue;
      float v = acc[qi][qj] * alpha + (biasb ? biasb[gn] : 0.f);
      if (act == 1) v = fmaxf(v, 0.f);
      else if (act == 2) v = (v > 30.f) ? v : log1pf(expf(v));
      Ob[(long)gm * o_sm + gn] = v;
    }
  }
}

// ---- chunked selective scan -----------------------------------------------
__global__ __launch_bounds__(256) void scanA_k(
    const float* __restrict__ xmc, const float* __restrict__ dt,
    const float* __restrict__ xdbl, const float* __restrict__ pk,
    float* __restrict__ SE, float* __restrict__ PC) {
  int g = threadIdx.x >> 4, n = threadIdx.x & 15;
  int r = blockIdx.x * 16 + g;
  int br = r >> 11, b = (r >> 9) & 3, d = r & 511;
  int c = blockIdx.y;
  const float* pb = pk + (long)br * BRS;
  float Aln = pb[35840 + d * 16 + n];
  long mbase = ((long)(br * 4 + b)) << 19;
  long xdb = (long)br * 196608 + (long)b * 49152;
  float s = 0.f, P = 1.f;
  int j0 = c * LCH;
  for (int j = j0; j < j0 + LCH; ++j) {
    long o = mbase + ((long)j << 9) + d;
    float delta = dt[o];
    float u = xmc[o];
    long xo = xdb + (long)j * 48;
    float Bv = xdbl[xo + 16 + n];
    float dA = exp2f(delta * Aln);
    s = fmaf(dA, s, delta * u * Bv);
    P *= dA;
  }
  long si = ((((long)(br * 4 + b)) * NCH + c) * 512 + d) * 16 + n;
  SE[si] = s;
  PC[si] = P;
}

__global__ __launch_bounds__(256) void scanB_k(const float* __restrict__ SE,
                                               const float* __restrict__ PC,
                                               float* __restrict__ SI) {
  long t = (long)blockIdx.x * 256 + threadIdx.x;   // < 98,304
  int n = (int)(t & 15);
  int d = (int)((t >> 4) & 511);
  int bb = (int)(t >> 13);
  float run = 0.f;
  for (int c = 0; c < NCH; ++c) {
    long si = (((long)bb * NCH + c) * 512 + d) * 16 + n;
    SI[si] = run;
    run = fmaf(PC[si], run, SE[si]);
  }
}

__global__ __launch_bounds__(256) void scanC_k(
    const float* __restrict__ xmc, const float* __restrict__ dt,
    const float* __restrict__ xdbl, const float* __restrict__ xz,
    const float* __restrict__ pk, const float* __restrict__ SI,
    u16* __restrict__ y) {
  int g = threadIdx.x >> 4, n = threadIdx.x & 15;
  int r = blockIdx.x * 16 + g;
  int br = r >> 11, b = (r >> 9) & 3, d = r & 511;
  int c = blockIdx.y;
  const float* pb = pk + (long)br * BRS;
  float Aln = pb[35840 + d * 16 + n];
  float Dv = pb[44032 + d];
  long mbase = ((long)(br * 4 + b)) << 19;
  long xdb = (long)br * 196608 + (long)b * 49152;
  long xzb = ((long)b << 20) + 512 + d;
  long si = ((((long)(br * 4 + b)) * NCH + c) * 512 + d) * 16 + n;
  float s = SI[si];
  int j0 = c * LCH;
  for (int j = j0; j < j0 + LCH; ++j) {
    long o = mbase + ((long)j << 9) + d;
    float delta = dt[o];
    float u = xmc[o];
    long xo = xdb + (long)j * 48;
    float Bv = xdbl[xo + 16 + n];
    float Cv = xdbl[xo + 32 + n];
    float dA = exp2f(delta * Aln);
    s = fmaf(dA, s, delta * u * Bv);
    float p = s * Cv;
    p += __shfl_xor(p, 1);
    p += __shfl_xor(p, 2);
    p += __shfl_xor(p, 4);
    p += __shfl_xor(p, 8);
    if (n == 0) {
      int l = brmap(br, j);
      float zv = xz[xzb + ((long)l << 10)];
      float sig = 1.f / (1.f + expf(-zv));
      y[o] = f2b((p + Dv * u) * (zv * sig));
    }
  }
}

// ---- combine 3 branch outputs -> COMBB bf16 (b,l,512) ---------------------
__global__ __launch_bounds__(256) void combine_k(const u16* __restrict__ y,
                                                 u16* __restrict__ comb) {
  long t = (long)blockIdx.x * 256 + threadIdx.x;   // < 2,097,152
  int d = (int)(t & 511);
  long r = t >> 9;
  int l = (int)(r & 1023);
  int b = (int)(r >> 10);
  int j2 = ((l & 63) << 4) | (l >> 6);
  float v = b2f(y[(((long)b << 10) + l) * 512 + d])
          + b2f(y[(((long)(4 + b) << 10) + (1023 - l)) * 512 + d])
          + b2f(y[(((long)(8 + b) << 10) + j2) * 512 + d]);
  comb[t] = f2b(v);
}

// ---- depthwise 3x3 conv + residual add, NCHW output -----------------------
__global__ __launch_bounds__(256) void dw_k(const float* __restrict__ xf,
                                            const float* __restrict__ dww,
                                            const float* __restrict__ dwb,
                                            const float* __restrict__ x,
                                            float* __restrict__ out) {
  int t = blockIdx.x;
  int b = t >> 5, h = t & 31;
  int c = threadIdx.x;
  float wv[9];
  #pragma unroll
  for (int k = 0; k < 9; ++k) wv[k] = dww[c * 9 + k];
  float bb = dwb[c];
  for (int w = 0; w < 32; ++w) {
    float acc = bb;
    #pragma unroll
    for (int kh = 0; kh < 3; ++kh) {
      int hh = h + kh - 1;
      if ((unsigned)hh >= 32u) continue;
      #pragma unroll
      for (int kw = 0; kw < 3; ++kw) {
        int ww = w + kw - 1;
        if ((unsigned)ww >= 32u) continue;
        acc = fmaf(xf[(((long)b << 10) + (hh << 5) + ww) * 256 + c],
                   wv[kh * 3 + kw], acc);
      }
    }
    long oi = (((long)b * 256 + c) * 32 + h) * 32 + w;
    out[oi] = acc + x[oi];
  }
}

// ---------------------------------------------------------------------------
extern "C" void kernel_launch(void* const* d_in, const int* in_sizes, int n_in,
                              void* d_out, int out_size, void* d_ws, size_t ws_size,
                              hipStream_t stream) {
  (void)in_sizes; (void)n_in; (void)out_size; (void)ws_size;
  const float* x    = (const float*)d_in[0];
  const float* p1w  = (const float*)d_in[1];
  const float* p1b  = (const float*)d_in[2];
  const float* p2w  = (const float*)d_in[3];
  const float* p2b  = (const float*)d_in[4];
  const float* nw   = (const float*)d_in[5];
  const float* nb   = (const float*)d_in[6];
  const float* qw   = (const float*)d_in[7];
  const float* qb   = (const float*)d_in[8];
  const float* kw   = (const float*)d_in[9];
  const float* kb   = (const float*)d_in[10];
  const float* vw   = (const float*)d_in[11];
  const float* vb   = (const float*)d_in[12];
  const float* ow   = (const float*)d_in[13];
  const float* ob   = (const float*)d_in[14];
  const float* fc1w = (const float*)d_in[15];
  const float* fc1b = (const float*)d_in[16];
  const float* dww  = (const float*)d_in[17];
  const float* dwb  = (const float*)d_in[18];
  const float* inw  = (const float*)d_in[19];
  const float* cw   = (const float*)d_in[20];
  const float* cb   = (const float*)d_in[21];
  const float* cbw  = (const float*)d_in[22];
  const float* cbb  = (const float*)d_in[23];
  const float* csw  = (const float*)d_in[24];
  const float* csb  = (const float*)d_in[25];
  const float* xpw  = (const float*)d_in[26];
  const float* xpbw = (const float*)d_in[27];
  const float* xpsw = (const float*)d_in[28];
  const float* dtw  = (const float*)d_in[29];
  const float* dtb  = (const float*)d_in[30];
  const float* dtbw = (const float*)d_in[31];
  const float* dtbb = (const float*)d_in[32];
  const float* dtsw = (const float*)d_in[33];
  const float* dtsb = (const float*)d_in[34];
  const float* Alog = (const float*)d_in[35];
  const float* Ablog= (const float*)d_in[36];
  const float* Aslog= (const float*)d_in[37];
  const float* Dv   = (const float*)d_in[38];
  const float* Dbv  = (const float*)d_in[39];
  const float* Dsv  = (const float*)d_in[40];
  const float* outw = (const float*)d_in[41];
  float* out = (float*)d_out;

  float* ws  = (float*)d_ws;
  float* W1T = ws;
  float* PB  = ws + 589824;
  u16*   WB  = (u16*)(ws + 723456);
  float* QBIAS = ws + 1116672;
  float* R   = ws + 1200000;
  // attn phase
  float* XCT   = R;
  u16*   XCTB  = (u16*)(R + 1100000);
  u16*   QKVB  = (u16*)(R + 1700000);
  u16*   VT    = (u16*)(R + 3300000);
  float* SC    = R + 3900000;
  u16*   P     = (u16*)(R + 12300000);
  u16*   ATTB  = (u16*)(R + 16500000);
  float* HS    = R + 17100000;
  u16*   XATTB = (u16*)(R + 18200000);
  // scan-persistent
  u16*   Y     = (u16*)(R + 18800000);
  float* XZ    = R + 22000000;
  // mamba phase
  float* XMC  = R;
  float* DT   = R + 6300000;
  float* XDBL = R + 12600000;
  float* SE   = R + 13200000;
  float* PC   = R + 14000000;
  float* SI   = R + 14800000;
  // tail phase
  u16*   COMBB = (u16*)R;
  float* XMB   = R + 600000;
  u16*   XM2B  = (u16*)(R + 1700000);
  u16*   XPB   = (u16*)(R + 2300000);
  float* XF    = R + 2900000;

  u16* WQKVB = WB;
  u16* OWB   = WB + 196608;
  u16* INWB  = WB + 262144;
  u16* OUTWB = WB + 524288;
  u16* P2WB  = WB + 655360;
  u16* FC1WB = WB + 720896;

  auto bgemm = [&](const u16* A, const u16* Bm, const float* bias,
                   float* OutF, u16* OutH, int M, int N, int K,
                   int lda, int ldb, int ldo, int nz, int zdiv,
                   long a_zb, long a_zh, long b_zb, long b_zh,
                   long o_zb, long o_zh, float alpha, int act) {
    dim3 g(M / 128, N / 128, nz);
    bgemm_k<<<g, 256, 0, stream>>>(A, Bm, bias, OutF, OutH, M, N, K,
                                   lda, ldb, ldo, zdiv, a_zb, a_zh,
                                   b_zb, b_zh, o_zb, o_zh, alpha, act);
  };

  // 0) pack params
  pack_w1t_k<<<2304, 256, 0, stream>>>(p1w, W1T);
  pack_branch_k<<<174, 256, 0, stream>>>(PB, cw, cb, xpw, dtw, dtb, Alog, Dv);
  pack_branch_k<<<174, 256, 0, stream>>>(PB + BRS, cbw, cbb, xpbw, dtbw, dtbb, Ablog, Dbv);
  pack_branch_k<<<174, 256, 0, stream>>>(PB + 2 * BRS, csw, csb, xpsw, dtsw, dtsb, Aslog, Dsv);
  pack_wb_k<<<3075, 256, 0, stream>>>(qw, kw, vw, ow, inw, outw, p2w, fc1w,
                                      qb, kb, vb, WB, QBIAS);

  // 1) conv1 (x_flat shuffle) -> XCT f32; LN -> XCTB bf16
  conv3x3_k<<<dim3(2, 128), 256, 0, stream>>>(x, W1T, p1b, XCT, nullptr, 0);
  layernorm_k<<<4096, 256, 0, stream>>>(XCT, nw, nb, XCTB);

  // 2) fused QKV -> QKVB bf16 [4096][768]
  bgemm(XCTB, WQKVB, QBIAS, nullptr, QKVB, 4096, 768, 256, 256, 256, 768,
        1, 1, 0, 0, 0, 0, 0, 0, 1.f, 0);
  vt_k<<<4096, 256, 0, stream>>>(QKVB, VT);

  // 3) scores f32 = QK^T/sqrt(128); softmax -> P bf16
  bgemm(QKVB, QKVB + 256, nullptr, SC, nullptr, 1024, 1024, 128, 768, 768, 1024,
        8, 2, 786432, 128, 786432, 128, 2097152, 1048576,
        0.08838834764831845f, 0);
  softmax_k<<<8192, 256, 0, stream>>>(SC, P);

  // 4) att = P @ V^T -> ATTB bf16 [4096][256]
  bgemm(P, VT, nullptr, nullptr, ATTB, 1024, 128, 1024, 1024, 1024, 256,
        8, 2, 2097152, 1048576, 262144, 131072, 262144, 128, 1.f, 0);

  // 5) o-projection -> HS f32; permute -> XATTB bf16
  bgemm(ATTB, OWB, ob, HS, nullptr, 4096, 256, 256, 256, 256, 256,
        1, 1, 0, 0, 0, 0, 0, 0, 1.f, 0);
  xatt_k<<<4096, 256, 0, stream>>>(HS, XATTB);

  // 6) xz = x_att @ in_w^T -> XZ f32 [4][1024][1024]
  bgemm(XATTB, INWB, nullptr, XZ, nullptr, 1024, 1024, 256, 256, 256, 1024,
        4, 1, 262144, 0, 0, 0, 1048576, 0, 1.f, 0);

  // 7) causal conv1d + silu
  cconv_k<<<24576, 256, 0, stream>>>(XZ, PB, XMC);

  // 8) x_dbl (f32 SIMT, N=48)
  {
    dim3 g(64, 1, 3);
    gemm_k<<<g, 256, 0, stream>>>(XMC, PB + 2560, nullptr, XDBL, 4096, 48, 512,
                                  512, 1, 512, 1, 48, 1, 2097152, 0, BRS, 0,
                                  196608, 0, 0, 1.f, 0);
  }
  // 9) dt = softplus(...) (f32 SIMT, K=16)
  {
    dim3 g(64, 8, 3);
    gemm_k<<<g, 256, 0, stream>>>(XDBL, PB + 27136, PB + 35328, DT, 4096, 512, 16,
                                  48, 1, 16, 1, 512, 1, 196608, 0, BRS, 0,
                                  2097152, 0, BRS, 1.f, 2);
  }

  // 10) chunked selective scan -> Y bf16
  scanA_k<<<dim3(384, NCH), 256, 0, stream>>>(XMC, DT, XDBL, PB, SE, PC);
  scanB_k<<<384, 256, 0, stream>>>(SE, PC, SI);
  scanC_k<<<dim3(384, NCH), 256, 0, stream>>>(XMC, DT, XDBL, XZ, PB, SI, Y);

  // 11) combine -> COMBB bf16
  combine_k<<<8192, 256, 0, stream>>>(Y, COMBB);

  // 12) mamba out projection -> XMB f32
  bgemm(COMBB, OUTWB, nullptr, XMB, nullptr, 4096, 256, 512, 512, 512, 256,
        1, 1, 0, 0, 0, 0, 0, 0, 1.f, 0);

  // 13) conv1 (NHWC) + relu -> XM2B bf16
  conv3x3_k<<<dim3(2, 128), 256, 0, stream>>>(XMB, W1T, p1b, nullptr, XM2B, 1);

  // 14) proj2 + relu -> XPB bf16
  bgemm(XM2B, P2WB, p2b, nullptr, XPB, 4096, 256, 256, 256, 256, 256,
        1, 1, 0, 0, 0, 0, 0, 0, 1.f, 1);

  // 15) fc1 -> XF f32
  bgemm(XPB, FC1WB, fc1b, XF, nullptr, 4096, 256, 256, 256, 256, 256,
        1, 1, 0, 0, 0, 0, 0, 0, 1.f, 0);

  // 16) depthwise 3x3 + residual -> out
  dw_k<<<128, 256, 0, stream>>>(XF, dww, dwb, x, out);
}

// Round 4
// 801.530 us; speedup vs baseline: 2.5214x; 1.2299x over previous
//
#include <hip/hip_runtime.h>

// ---------------------------------------------------------------------------
// Att_MambaLayer: bf16-MFMA GEMMs + MFMA convs + chunked scan w/ DPP reduce.
// B=4, C=256, H=W=32, N=l=1024, NH=2, dh=128, DI=512, DS=16, DTR=16.
// ---------------------------------------------------------------------------

#define LOG2E 1.4426950408889634f
#define NCH 8
#define LCH 128

typedef unsigned short u16;
typedef unsigned int u32;
typedef __attribute__((ext_vector_type(8))) short bf16x8;
typedef __attribute__((ext_vector_type(4))) float f32x4;

__device__ __forceinline__ u16 f2b(float f) {
  u32 u = __builtin_bit_cast(u32, f);
  u32 r = (u + 0x7fffu + ((u >> 16) & 1u)) >> 16;
  return (u16)r;
}
__device__ __forceinline__ float b2f(u16 h) {
  u32 u = ((u32)h) << 16;
  return __builtin_bit_cast(float, u);
}

// DPP add: p + p[lane ^ mask] via gfx9 DPP row ops (no DS, pure VALU)
#define DPP_ADD(p, ctrl)                                                   \
  (p) += __builtin_bit_cast(float, __builtin_amdgcn_update_dpp(            \
             0, __builtin_bit_cast(int, (p)), ctrl, 0xF, 0xF, true))

static const long BRS = 44544;

// ---------------------------------------------------------------------------
__device__ __forceinline__ float block_reduce256(float v, int op) {
  #pragma unroll
  for (int m = 32; m; m >>= 1) {
    float o = __shfl_xor(v, m);
    v = op ? fmaxf(v, o) : v + o;
  }
  __shared__ float sm[4];
  if ((threadIdx.x & 63) == 0) sm[threadIdx.x >> 6] = v;
  __syncthreads();
  v = op ? fmaxf(fmaxf(sm[0], sm[1]), fmaxf(sm[2], sm[3]))
         : (sm[0] + sm[1] + sm[2] + sm[3]);
  __syncthreads();
  return v;
}

// ---- param packing --------------------------------------------------------
__global__ __launch_bounds__(256) void pack_branch_k(
    float* __restrict__ dst, const float* __restrict__ cw,
    const float* __restrict__ cb, const float* __restrict__ xpw,
    const float* __restrict__ dtw, const float* __restrict__ dtb,
    const float* __restrict__ Alog, const float* __restrict__ Dv) {
  int t = blockIdx.x * 256 + threadIdx.x;
  if (t < 2048) dst[t] = cw[t];
  else if (t < 2560) dst[t] = cb[t - 2048];
  else if (t < 27136) dst[t] = xpw[t - 2560];
  else if (t < 35328) dst[t] = dtw[t - 27136];
  else if (t < 35840) dst[t] = dtb[t - 35328];
  else if (t < 44032) dst[t] = -expf(Alog[t - 35840]) * LOG2E;
  else if (t < 44544) dst[t] = Dv[t - 44032];
}

__global__ __launch_bounds__(256) void pack_wb_k(
    const float* __restrict__ qw, const float* __restrict__ kw,
    const float* __restrict__ vw, const float* __restrict__ ow,
    const float* __restrict__ inw, const float* __restrict__ outw,
    const float* __restrict__ p2w, const float* __restrict__ fc1w,
    const float* __restrict__ qb, const float* __restrict__ kb,
    const float* __restrict__ vb, u16* __restrict__ WB,
    float* __restrict__ QBIAS) {
  int t = blockIdx.x * 256 + threadIdx.x;   // < 787,200
  if (t < 65536) WB[t] = f2b(qw[t]);
  else if (t < 131072) WB[t] = f2b(kw[t - 65536]);
  else if (t < 196608) WB[t] = f2b(vw[t - 131072]);
  else if (t < 262144) WB[t] = f2b(ow[t - 196608]);
  else if (t < 524288) WB[t] = f2b(inw[t - 262144]);
  else if (t < 655360) WB[t] = f2b(outw[t - 524288]);
  else if (t < 720896) WB[t] = f2b(p2w[t - 655360]);
  else if (t < 786432) WB[t] = f2b(fc1w[t - 720896]);
  else if (t < 787200) {
    int i = t - 786432;
    QBIAS[i] = (i < 256) ? qb[i] : (i < 512 ? kb[i - 256] : vb[i - 512]);
  }
}

// conv weight pack: wc[co][(kh*3+kw)*256+ci] = w[co][ci][kh][kw]
__global__ __launch_bounds__(256) void pack_wc_k(const float* __restrict__ w,
                                                 u16* __restrict__ wc) {
  int t = blockIdx.x * 256 + threadIdx.x;   // < 589,824
  int ci = t & 255, khw = (t >> 8) % 9, co = t / 2304;
  wc[t] = f2b(w[co * 2304 + ci * 9 + khw]);
}

// x input -> shuffled NHWC bf16 (the x_flat permutation)
__global__ __launch_bounds__(256) void xin_k(const float* __restrict__ x,
                                             u16* __restrict__ xin) {
  int t = blockIdx.x * 256 + threadIdx.x;   // < 1,048,576
  int ci = t & 255, w = (t >> 8) & 31, h = (t >> 13) & 31, b = t >> 18;
  int idx = ci * 32 + h;
  xin[t] = f2b(x[((long)b << 18) + ((long)(idx & 255) << 10) +
                 ((idx >> 8) << 5) + w]);
}

// ---- MFMA 3x3 conv: out[l][co] = act(sum_{kh,kw,ci} in[l+sh][ci]*wc + b) ---
// in: [4096][256] bf16 NHWC; wc: [256][2304] k=(kh*3+kw)*256+ci.
// grid (64, 4): tile 64 rows x 64 cols, 4 waves (one 16-row band each).
__global__ __launch_bounds__(256, 2) void conv_mfma_k(
    const u16* __restrict__ in, const u16* __restrict__ wc,
    const float* __restrict__ bias, float* __restrict__ outF,
    u16* __restrict__ outH, int relu) {
  __shared__ u16 ldsA[4][64][8];
  __shared__ u16 ldsB[4][64][8];
  int m0 = blockIdx.x * 64, n0 = blockIdx.y * 64;
  int tid = threadIdx.x;
  int lane = tid & 63, wv = tid >> 6;
  int row = tid & 63, k8 = tid >> 6;
  int l = m0 + row;
  int h = (l >> 5) & 31, w = l & 31;
  int rlo = lane & 15, khl = lane >> 4;
  f32x4 acc[4];
  #pragma unroll
  for (int n = 0; n < 4; ++n) acc[n] = (f32x4){0.f, 0.f, 0.f, 0.f};
  for (int t = 0; t < 72; ++t) {
    int kh = t / 24, r = t % 24, kw = r >> 3, ci0 = (r & 7) << 5;
    __syncthreads();
    bf16x8 av = (bf16x8){0, 0, 0, 0, 0, 0, 0, 0};
    int hh = h + kh - 1, ww = w + kw - 1;
    if ((unsigned)hh < 32u && (unsigned)ww < 32u)
      av = *(const bf16x8*)&in[(long)(l + (kh - 1) * 32 + (kw - 1)) * 256 +
                               ci0 + k8 * 8];
    *(bf16x8*)&ldsA[k8][row][0] = av;
    *(bf16x8*)&ldsB[k8][row][0] =
        *(const bf16x8*)&wc[(long)(n0 + row) * 2304 + t * 32 + k8 * 8];
    __syncthreads();
    bf16x8 af = *(const bf16x8*)&ldsA[khl][wv * 16 + rlo][0];
    #pragma unroll
    for (int n = 0; n < 4; ++n) {
      bf16x8 bf = *(const bf16x8*)&ldsB[khl][n * 16 + rlo][0];
      acc[n] = __builtin_amdgcn_mfma_f32_16x16x32_bf16(af, bf, acc[n], 0, 0, 0);
    }
  }
  int rowb = (lane >> 4) * 4;
  #pragma unroll
  for (int n = 0; n < 4; ++n) {
    int gn = n0 + n * 16 + rlo;
    float bv = bias[gn];
    #pragma unroll
    for (int j = 0; j < 4; ++j) {
      int gm = m0 + wv * 16 + rowb + j;
      float v = acc[n][j] + bv;
      if (relu) v = fmaxf(v, 0.f);
      long oi = (long)gm * 256 + gn;
      if (outH) outH[oi] = f2b(v);
      else outF[oi] = v;
    }
  }
}

// ---- LayerNorm rows of 256 -> bf16 ----------------------------------------
__global__ __launch_bounds__(256) void layernorm_k(const float* __restrict__ x,
                                                   const float* __restrict__ w,
                                                   const float* __restrict__ b,
                                                   u16* __restrict__ o) {
  const float* p = x + (long)blockIdx.x * 256;
  float v = p[threadIdx.x];
  float mean = block_reduce256(v, 0) * (1.f / 256.f);
  float d = v - mean;
  float var = block_reduce256(d * d, 0) * (1.f / 256.f);
  o[(long)blockIdx.x * 256 + threadIdx.x] =
      f2b(d * rsqrtf(var + 1e-5f) * w[threadIdx.x] + b[threadIdx.x]);
}

// ---- softmax rows of 1024: f32 in, bf16 out -------------------------------
__global__ __launch_bounds__(256) void softmax_k(const float* __restrict__ S,
                                                 u16* __restrict__ P) {
  const float* p = S + (long)blockIdx.x * 1024;
  u16* q = P + (long)blockIdx.x * 1024;
  float4 v = ((const float4*)p)[threadIdx.x];
  float m = fmaxf(fmaxf(v.x, v.y), fmaxf(v.z, v.w));
  m = block_reduce256(m, 1);
  v.x = expf(v.x - m); v.y = expf(v.y - m);
  v.z = expf(v.z - m); v.w = expf(v.w - m);
  float s = block_reduce256(v.x + v.y + v.z + v.w, 0);
  float inv = 1.f / s;
  u32 lo = (u32)f2b(v.x * inv) | ((u32)f2b(v.y * inv) << 16);
  u32 hi = (u32)f2b(v.z * inv) | ((u32)f2b(v.w * inv) << 16);
  ((uint2*)q)[threadIdx.x] = make_uint2(lo, hi);
}

// ---- bf16 MFMA GEMM: Out = act(alpha * A @ B^T + bias) --------------------
__global__ __launch_bounds__(256, 2) void bgemm_k(
    const u16* __restrict__ A, const u16* __restrict__ B,
    const float* __restrict__ bias, float* __restrict__ OutF,
    u16* __restrict__ OutH, int M, int N, int K,
    int lda, int ldb, int ldo, int zdiv,
    long a_zb, long a_zh, long b_zb, long b_zh, long o_zb, long o_zh,
    float alpha, int act) {
  __shared__ u16 ldsA[4][128][8];
  __shared__ u16 ldsB[4][128][8];
  int z = blockIdx.z, zb = z / zdiv, zh = z - zb * zdiv;
  const u16* Ab = A + zb * a_zb + zh * a_zh;
  const u16* Bb = B + zb * b_zb + zh * b_zh;
  long ob = zb * o_zb + zh * o_zh;
  int m0 = blockIdx.x * 128, n0 = blockIdx.y * 128;
  int tid = threadIdx.x;
  int lane = tid & 63, wv = tid >> 6;
  int wr = wv >> 1, wc = wv & 1;
  int r1 = tid & 127, h1 = tid >> 7;
  int r2 = r1, h2 = h1 + 2;
  const u16* a1 = Ab + (long)(m0 + r1) * lda + h1 * 8;
  const u16* a2 = Ab + (long)(m0 + r2) * lda + h2 * 8;
  const u16* b1 = Bb + (long)(n0 + r1) * ldb + h1 * 8;
  const u16* b2 = Bb + (long)(n0 + r2) * ldb + h2 * 8;

  f32x4 acc[4][4];
  #pragma unroll
  for (int i = 0; i < 4; ++i)
    #pragma unroll
    for (int j = 0; j < 4; ++j) acc[i][j] = (f32x4){0.f, 0.f, 0.f, 0.f};

  bf16x8 ra1 = *(const bf16x8*)a1;
  bf16x8 ra2 = *(const bf16x8*)a2;
  bf16x8 rb1 = *(const bf16x8*)b1;
  bf16x8 rb2 = *(const bf16x8*)b2;

  int nt = K >> 5;
  int kh = lane >> 4, rlo = lane & 15;
  for (int t = 0; t < nt; ++t) {
    __syncthreads();
    *(bf16x8*)&ldsA[h1][r1][0] = ra1;
    *(bf16x8*)&ldsA[h2][r2][0] = ra2;
    *(bf16x8*)&ldsB[h1][r1][0] = rb1;
    *(bf16x8*)&ldsB[h2][r2][0] = rb2;
    if (t + 1 < nt) {
      int ko = (t + 1) << 5;
      ra1 = *(const bf16x8*)(a1 + ko);
      ra2 = *(const bf16x8*)(a2 + ko);
      rb1 = *(const bf16x8*)(b1 + ko);
      rb2 = *(const bf16x8*)(b2 + ko);
    }
    __syncthreads();
    bf16x8 af[4], bfr[4];
    #pragma unroll
    for (int m = 0; m < 4; ++m)
      af[m] = *(const bf16x8*)&ldsA[kh][wr * 64 + m * 16 + rlo][0];
    #pragma unroll
    for (int n = 0; n < 4; ++n)
      bfr[n] = *(const bf16x8*)&ldsB[kh][wc * 64 + n * 16 + rlo][0];
    #pragma unroll
    for (int m = 0; m < 4; ++m)
      #pragma unroll
      for (int n = 0; n < 4; ++n)
        acc[m][n] = __builtin_amdgcn_mfma_f32_16x16x32_bf16(af[m], bfr[n],
                                                            acc[m][n], 0, 0, 0);
  }
  int rowb = (lane >> 4) * 4;
  #pragma unroll
  for (int m = 0; m < 4; ++m) {
    #pragma unroll
    for (int n = 0; n < 4; ++n) {
      int gn = n0 + wc * 64 + n * 16 + rlo;
      float bv = bias ? bias[gn] : 0.f;
      #pragma unroll
      for (int j = 0; j < 4; ++j) {
        int gm = m0 + wr * 64 + m * 16 + rowb + j;
        float v = acc[m][n][j] * alpha + bv;
        if (act == 1) v = fmaxf(v, 0.f);
        long oi = ob + (long)gm * ldo + gn;
        if (OutH) OutH[oi] = f2b(v);
        else OutF[oi] = v;
      }
    }
  }
}

// ---- V transpose ----------------------------------------------------------
__global__ __launch_bounds__(256) void vt_k(const u16* __restrict__ qkv,
                                            u16* __restrict__ vt) {
  int t = blockIdx.x * 256 + threadIdx.x;    // < 1,048,576
  int j = t & 1023, d = (t >> 10) & 127, bh = t >> 17;
  int b = bh >> 1, h = bh & 1;
  vt[t] = qkv[((long)(b * 1024 + j)) * 768 + 512 + h * 128 + d];
}

// ---- x_att permute --------------------------------------------------------
__global__ __launch_bounds__(256) void xatt_k(const float* __restrict__ hs,
                                              u16* __restrict__ xa) {
  int t = blockIdx.x * 256 + threadIdx.x;    // < 1,048,576
  int dm = t & 255, l = (t >> 8) & 1023, b = t >> 18;
  xa[t] = f2b(hs[((long)b << 18) + dm * 1024 + l]);
}

// ---- branch sequence index map --------------------------------------------
__device__ __forceinline__ int brmap(int br, int j) {
  if (br == 0) return j;
  if (br == 1) return 1023 - j;
  return ((j & 15) << 6) | (j >> 4);
}

// ---- causal conv1d (k=4) + silu; also precompute silu(z) ------------------
__global__ __launch_bounds__(256) void cconv_k(const float* __restrict__ xz,
                                               const float* __restrict__ pk,
                                               float* __restrict__ xmc,
                                               float* __restrict__ zs) {
  long t = (long)blockIdx.x * 256 + threadIdx.x;   // < 6,291,456
  int d = (int)(t & 511);
  long r = t >> 9;
  int j = (int)(r & 1023);
  int bb = (int)(r >> 10);
  int b = bb & 3, br = bb >> 2;
  const float* pb = pk + (long)br * BRS;
  float acc = pb[2048 + d];
  #pragma unroll
  for (int tap = 0; tap < 4; ++tap) {
    int jj = j - 3 + tap;
    if (jj >= 0) {
      int l = brmap(br, jj);
      acc = fmaf(xz[(((long)b << 10) + l) * 1024 + d], pb[d * 4 + tap], acc);
    }
  }
  float sig = 1.f / (1.f + expf(-acc));
  xmc[t] = acc * sig;
  int l = brmap(br, j);
  float zv = xz[(((long)b << 10) + l) * 1024 + 512 + d];
  zs[t] = zv / (1.f + expf(-zv));
}

// ---- f32 SIMT GEMM (small shapes; act3 packs (delta,u) float2) ------------
__global__ __launch_bounds__(256) void gemm_k(
    const float* __restrict__ A, const float* __restrict__ B,
    const float* __restrict__ bias, float* __restrict__ Out,
    int M, int N, int K,
    int a_sm, int a_sk, int b_sn, int b_sk, int o_sm,
    int zdiv, long a_zb, long a_zh, long b_zb, long b_zh, long o_zb, long o_zh,
    long bias_zb, float alpha, int act, const float* __restrict__ Aux) {
  int z = blockIdx.z, zb = z / zdiv, zh = z % zdiv;
  const float* Ab = A + zb * a_zb + zh * a_zh;
  const float* Bb = B + zb * b_zb + zh * b_zh;
  const float* biasb = bias ? (bias + zb * bias_zb) : nullptr;
  long oo = zb * o_zb + zh * o_zh;
  __shared__ float As[16][68];
  __shared__ float Bs[16][68];
  int m0 = blockIdx.x * 64, n0 = blockIdx.y * 64;
  int tid = threadIdx.x;
  int tm = tid >> 4, tn = tid & 15;
  float acc[4][4] = {};
  for (int k0 = 0; k0 < K; k0 += 16) {
    #pragma unroll
    for (int it = 0; it < 4; ++it) {
      int i = tid + it * 256;
      if (a_sk == 1) {
        int rr = i >> 4, kk = i & 15;
        int gm = m0 + rr, gk = k0 + kk;
        float av = 0.f;
        if (gm < M && gk < K) av = Ab[(long)gm * a_sm + gk];
        As[kk][rr] = av;
      } else {
        int rr = i & 63, kk = i >> 6;
        int gm = m0 + rr, gk = k0 + kk;
        float av = 0.f;
        if (gm < M && gk < K) av = Ab[(long)gm * a_sm + (long)gk * a_sk];
        As[kk][rr] = av;
      }
      if (b_sk == 1) {
        int rr = i >> 4, kk = i & 15;
        int gn = n0 + rr, gk = k0 + kk;
        float bv = 0.f;
        if (gn < N && gk < K) bv = Bb[(long)gn * b_sn + gk];
        Bs[kk][rr] = bv;
      } else {
        int rr = i & 63, kk = i >> 6;
        int gn = n0 + rr, gk = k0 + kk;
        float bv = 0.f;
        if (gn < N && gk < K) bv = Bb[(long)gn * b_sn + (long)gk * b_sk];
        Bs[kk][rr] = bv;
      }
    }
    __syncthreads();
    #pragma unroll
    for (int kk = 0; kk < 16; ++kk) {
      float ar[4], br_[4];
      #pragma unroll
      for (int q = 0; q < 4; ++q) ar[q] = As[kk][tm * 4 + q];
      #pragma unroll
      for (int q = 0; q < 4; ++q) br_[q] = Bs[kk][tn * 4 + q];
      #pragma unroll
      for (int qi = 0; qi < 4; ++qi)
        #pragma unroll
        for (int qj = 0; qj < 4; ++qj)
          acc[qi][qj] = fmaf(ar[qi], br_[qj], acc[qi][qj]);
    }
    __syncthreads();
  }
  #pragma unroll
  for (int qi = 0; qi < 4; ++qi) {
    int gm = m0 + tm * 4 + qi;
    if (gm >= M) continue;
    #pragma unroll
    for (int qj = 0; qj < 4; ++qj) {
      int gn = n0 + tn * 4 + qj;
      if (gn >= N) continue;
      float v = acc[qi][qj] * alpha + (biasb ? biasb[gn] : 0.f);
      long oid = oo + (long)gm * o_sm + gn;
      if (act == 3) {
        float sp = (v > 30.f) ? v : log1pf(expf(v));
        ((float2*)Out)[oid] = make_float2(sp, Aux[oid]);
      } else {
        if (act == 1) v = fmaxf(v, 0.f);
        else if (act == 2) v = (v > 30.f) ? v : log1pf(expf(v));
        Out[oid] = v;
      }
    }
  }
}

// ---- chunked selective scan -----------------------------------------------
// blocks: (384, NCH); 16 groups of 16 lanes; same (br,b) per block; B/C in LDS.

__global__ __launch_bounds__(256) void scanA_k(
    const float2* __restrict__ du, const float* __restrict__ xdbl,
    const float* __restrict__ pk, float* __restrict__ SE,
    float* __restrict__ PC) {
  __shared__ float bs[LCH][16];
  int g = threadIdx.x >> 4, n = threadIdx.x & 15;
  int r0 = blockIdx.x * 16;
  int br = r0 >> 11, b = (r0 >> 9) & 3, d = (r0 & 511) + g;
  int c = blockIdx.y;
  long xdb = (long)br * 196608 + (long)b * 49152 + (long)c * LCH * 48;
  {
    int f0 = threadIdx.x * 8;
    int j = f0 >> 4, nn = f0 & 15;
    const float4* s4 = (const float4*)&xdbl[xdb + j * 48 + 16 + nn];
    *(float4*)&bs[j][nn] = s4[0];
    *(float4*)&bs[j][nn + 4] = s4[1];
  }
  __syncthreads();
  const float* pb = pk + (long)br * BRS;
  float Aln = pb[35840 + d * 16 + n];
  long obase = (((long)(br * 4 + b)) << 19) + (long)(c * LCH) * 512 + d;
  const float2* pdu = du + obase;
  float s = 0.f, P = 1.f;
  #pragma unroll 4
  for (int jl = 0; jl < LCH; ++jl) {
    float2 dv = pdu[(long)jl * 512];
    float dA = exp2f(dv.x * Aln);
    s = fmaf(dA, s, dv.x * dv.y * bs[jl][n]);
    P *= dA;
  }
  long si = ((((long)(br * 4 + b)) * NCH + c) * 512 + d) * 16 + n;
  SE[si] = s;
  PC[si] = P;
}

__global__ __launch_bounds__(256) void scanB_k(const float* __restrict__ SE,
                                               const float* __restrict__ PC,
                                               float* __restrict__ SI) {
  long t = (long)blockIdx.x * 256 + threadIdx.x;   // < 98,304
  int n = (int)(t & 15);
  int d = (int)((t >> 4) & 511);
  int bb = (int)(t >> 13);
  float run = 0.f;
  for (int c = 0; c < NCH; ++c) {
    long si = (((long)bb * NCH + c) * 512 + d) * 16 + n;
    SI[si] = run;
    run = fmaf(PC[si], run, SE[si]);
  }
}

__global__ __launch_bounds__(256) void scanC_k(
    const float2* __restrict__ du, const float* __restrict__ xdbl,
    const float* __restrict__ zs, const float* __restrict__ pk,
    const float* __restrict__ SI, u16* __restrict__ y) {
  __shared__ float bcs[LCH][32];
  int g = threadIdx.x >> 4, n = threadIdx.x & 15;
  int r0 = blockIdx.x * 16;
  int br = r0 >> 11, b = (r0 >> 9) & 3, d = (r0 & 511) + g;
  int c = blockIdx.y;
  long xdb = (long)br * 196608 + (long)b * 49152 + (long)c * LCH * 48;
  {
    int f0 = threadIdx.x * 16;
    int j = f0 >> 5, nn = f0 & 31;
    const float4* s4 = (const float4*)&xdbl[xdb + j * 48 + 16 + nn];
    *(float4*)&bcs[j][nn] = s4[0];
    *(float4*)&bcs[j][nn + 4] = s4[1];
    *(float4*)&bcs[j][nn + 8] = s4[2];
    *(float4*)&bcs[j][nn + 12] = s4[3];
  }
  __syncthreads();
  const float* pb = pk + (long)br * BRS;
  float Aln = pb[35840 + d * 16 + n];
  float Dv = pb[44032 + d];
  long obase = (((long)(br * 4 + b)) << 19) + (long)(c * LCH) * 512 + d;
  long si = ((((long)(br * 4 + b)) * NCH + c) * 512 + d) * 16 + n;
  float s = SI[si];
  const float2* pdu = du + obase;
  const float* pzs = zs + obase;
  u16* py = y + obase;
  #pragma unroll 4
  for (int jl = 0; jl < LCH; ++jl) {
    float2 dv = pdu[(long)jl * 512];
    float dA = exp2f(dv.x * Aln);
    s = fmaf(dA, s, dv.x * dv.y * bcs[jl][n]);
    float p = s * bcs[jl][16 + n];
    DPP_ADD(p, 0xB1);    // xor 1 (quad_perm [1,0,3,2])
    DPP_ADD(p, 0x4E);    // xor 2 (quad_perm [2,3,0,1])
    DPP_ADD(p, 0x141);   // xor 7 (row_half_mirror)
    DPP_ADD(p, 0x140);   // xor 15 (row_mirror)
    if (n == 0)
      py[(long)jl * 512] = f2b((p + Dv * dv.y) * pzs[(long)jl * 512]);
  }
}

// ---- combine 3 branch outputs -> COMBB bf16 (b,l,512) ---------------------
__global__ __launch_bounds__(256) void combine_k(const u16* __restrict__ y,
                                                 u16* __restrict__ comb) {
  long t = (long)blockIdx.x * 256 + threadIdx.x;   // < 2,097,152
  int d = (int)(t & 511);
  long r = t >> 9;
  int l = (int)(r & 1023);
  int b = (int)(r >> 10);
  int j2 = ((l & 63) << 4) | (l >> 6);
  float v = b2f(y[(((long)b << 10) + l) * 512 + d])
          + b2f(y[(((long)(4 + b) << 10) + (1023 - l)) * 512 + d])
          + b2f(y[(((long)(8 + b) << 10) + j2) * 512 + d]);
  comb[t] = f2b(v);
}

// ---- depthwise 3x3 conv + residual add, NCHW output -----------------------
__global__ __launch_bounds__(256) void dw_k(const float* __restrict__ xf,
                                            const float* __restrict__ dww,
                                            const float* __restrict__ dwb,
                                            const float* __restrict__ x,
                                            float* __restrict__ out) {
  int t = blockIdx.x;
  int b = t >> 5, h = t & 31;
  int c = threadIdx.x;
  float wv[9];
  #pragma unroll
  for (int k = 0; k < 9; ++k) wv[k] = dww[c * 9 + k];
  float bb = dwb[c];
  for (int w = 0; w < 32; ++w) {
    float acc = bb;
    #pragma unroll
    for (int kh = 0; kh < 3; ++kh) {
      int hh = h + kh - 1;
      if ((unsigned)hh >= 32u) continue;
      #pragma unroll
      for (int kw = 0; kw < 3; ++kw) {
        int ww = w + kw - 1;
        if ((unsigned)ww >= 32u) continue;
        acc = fmaf(xf[(((long)b << 10) + (hh << 5) + ww) * 256 + c],
                   wv[kh * 3 + kw], acc);
      }
    }
    long oi = (((long)b * 256 + c) * 32 + h) * 32 + w;
    out[oi] = acc + x[oi];
  }
}

// ---------------------------------------------------------------------------
extern "C" void kernel_launch(void* const* d_in, const int* in_sizes, int n_in,
                              void* d_out, int out_size, void* d_ws, size_t ws_size,
                              hipStream_t stream) {
  (void)in_sizes; (void)n_in; (void)out_size; (void)ws_size;
  const float* x    = (const float*)d_in[0];
  const float* p1w  = (const float*)d_in[1];
  const float* p1b  = (const float*)d_in[2];
  const float* p2w  = (const float*)d_in[3];
  const float* p2b  = (const float*)d_in[4];
  const float* nw   = (const float*)d_in[5];
  const float* nb   = (const float*)d_in[6];
  const float* qw   = (const float*)d_in[7];
  const float* qb   = (const float*)d_in[8];
  const float* kw   = (const float*)d_in[9];
  const float* kb   = (const float*)d_in[10];
  const float* vw   = (const float*)d_in[11];
  const float* vb   = (const float*)d_in[12];
  const float* ow   = (const float*)d_in[13];
  const float* ob   = (const float*)d_in[14];
  const float* fc1w = (const float*)d_in[15];
  const float* fc1b = (const float*)d_in[16];
  const float* dww  = (const float*)d_in[17];
  const float* dwb  = (const float*)d_in[18];
  const float* inw  = (const float*)d_in[19];
  const float* cw   = (const float*)d_in[20];
  const float* cb   = (const float*)d_in[21];
  const float* cbw  = (const float*)d_in[22];
  const float* cbb  = (const float*)d_in[23];
  const float* csw  = (const float*)d_in[24];
  const float* csb  = (const float*)d_in[25];
  const float* xpw  = (const float*)d_in[26];
  const float* xpbw = (const float*)d_in[27];
  const float* xpsw = (const float*)d_in[28];
  const float* dtw  = (const float*)d_in[29];
  const float* dtb  = (const float*)d_in[30];
  const float* dtbw = (const float*)d_in[31];
  const float* dtbb = (const float*)d_in[32];
  const float* dtsw = (const float*)d_in[33];
  const float* dtsb = (const float*)d_in[34];
  const float* Alog = (const float*)d_in[35];
  const float* Ablog= (const float*)d_in[36];
  const float* Aslog= (const float*)d_in[37];
  const float* Dv   = (const float*)d_in[38];
  const float* Dbv  = (const float*)d_in[39];
  const float* Dsv  = (const float*)d_in[40];
  const float* outw = (const float*)d_in[41];
  float* out = (float*)d_out;

  float* ws    = (float*)d_ws;
  float* PB    = ws;
  u16*   WCONV = (u16*)(ws + 140000);
  u16*   WB    = (u16*)(ws + 440000);
  float* QBIAS = ws + 840000;
  u16*   XINB  = (u16*)(ws + 850000);
  float* R     = ws + 1400000;
  // scan-persistent / mamba
  float*  XZ   = R;                         // dead after cconv
  float2* DU   = (float2*)R;                // written by dt-gemm (XZ dead)
  float*  XMC  = R + 12700000;              // dead after dt-gemm, zone reused:
  u16*    Y    = (u16*)(R + 12700000);
  float*  SE   = R + 15900000;
  float*  PC   = R + 16700000;
  u16*   COMBB = (u16*)(R + 17500000);
  float*  ZS   = R + 19100000;
  float*  XDBL = R + 25400000;
  float*  SI   = R + 26000000;
  // attn phase (dead before mamba phase)
  float* XCT   = R + 4300000;
  u16*   XCTB  = (u16*)(R + 5400000);
  u16*   QKVB  = (u16*)(R + 6000000);
  u16*   VT    = (u16*)(R + 7600000);
  float* SC    = R + 8200000;
  u16*   P     = (u16*)(R + 16600000);
  u16*   ATTB  = (u16*)(R + 18800000);
  float* HS    = R + 19400000;
  u16*   XATTB = (u16*)(R + 20500000);
  // tail phase (DU/ZS/etc dead)
  u16*   XMBB  = (u16*)R;
  u16*   XM2B  = (u16*)(R + 600000);
  u16*   XPB   = (u16*)(R + 1200000);
  float* XF    = R + 1800000;

  u16* WQKVB = WB;
  u16* OWB   = WB + 196608;
  u16* INWB  = WB + 262144;
  u16* OUTWB = WB + 524288;
  u16* P2WB  = WB + 655360;
  u16* FC1WB = WB + 720896;

  auto bgemm = [&](const u16* A, const u16* Bm, const float* bias,
                   float* OutF, u16* OutH, int M, int N, int K,
                   int lda, int ldb, int ldo, int nz, int zdiv,
                   long a_zb, long a_zh, long b_zb, long b_zh,
                   long o_zb, long o_zh, float alpha, int act) {
    dim3 g(M / 128, N / 128, nz);
    bgemm_k<<<g, 256, 0, stream>>>(A, Bm, bias, OutF, OutH, M, N, K,
                                   lda, ldb, ldo, zdiv, a_zb, a_zh,
                                   b_zb, b_zh, o_zb, o_zh, alpha, act);
  };

  // 0) pack params
  pack_branch_k<<<174, 256, 0, stream>>>(PB, cw, cb, xpw, dtw, dtb, Alog, Dv);
  pack_branch_k<<<174, 256, 0, stream>>>(PB + BRS, cbw, cbb, xpbw, dtbw, dtbb, Ablog, Dbv);
  pack_branch_k<<<174, 256, 0, stream>>>(PB + 2 * BRS, csw, csb, xpsw, dtsw, dtsb, Aslog, Dsv);
  pack_wb_k<<<3075, 256, 0, stream>>>(qw, kw, vw, ow, inw, outw, p2w, fc1w,
                                      qb, kb, vb, WB, QBIAS);
  pack_wc_k<<<2304, 256, 0, stream>>>(p1w, WCONV);
  xin_k<<<4096, 256, 0, stream>>>(x, XINB);

  // 1) conv1 (MFMA, shuffled input) -> XCT f32; LN -> XCTB bf16
  conv_mfma_k<<<dim3(64, 4), 256, 0, stream>>>(XINB, WCONV, p1b, XCT, nullptr, 0);
  layernorm_k<<<4096, 256, 0, stream>>>(XCT, nw, nb, XCTB);

  // 2) fused QKV -> QKVB bf16 [4096][768]
  bgemm(XCTB, WQKVB, QBIAS, nullptr, QKVB, 4096, 768, 256, 256, 256, 768,
        1, 1, 0, 0, 0, 0, 0, 0, 1.f, 0);
  vt_k<<<4096, 256, 0, stream>>>(QKVB, VT);

  // 3) scores f32 = QK^T/sqrt(128); softmax -> P bf16
  bgemm(QKVB, QKVB + 256, nullptr, SC, nullptr, 1024, 1024, 128, 768, 768, 1024,
        8, 2, 786432, 128, 786432, 128, 2097152, 1048576,
        0.08838834764831845f, 0);
  softmax_k<<<8192, 256, 0, stream>>>(SC, P);

  // 4) att = P @ V^T -> ATTB bf16 [4096][256]
  bgemm(P, VT, nullptr, nullptr, ATTB, 1024, 128, 1024, 1024, 1024, 256,
        8, 2, 2097152, 1048576, 262144, 131072, 262144, 128, 1.f, 0);

  // 5) o-projection -> HS f32; permute -> XATTB bf16
  bgemm(ATTB, OWB, ob, HS, nullptr, 4096, 256, 256, 256, 256, 256,
        1, 1, 0, 0, 0, 0, 0, 0, 1.f, 0);
  xatt_k<<<4096, 256, 0, stream>>>(HS, XATTB);

  // 6) xz = x_att @ in_w^T -> XZ f32 [4][1024][1024]
  bgemm(XATTB, INWB, nullptr, XZ, nullptr, 1024, 1024, 256, 256, 256, 1024,
        4, 1, 262144, 0, 0, 0, 1048576, 0, 1.f, 0);

  // 7) causal conv1d + silu -> XMC; silu(z) -> ZS
  cconv_k<<<24576, 256, 0, stream>>>(XZ, PB, XMC, ZS);

  // 8) x_dbl (f32 SIMT, N=48)
  {
    dim3 g(64, 1, 3);
    gemm_k<<<g, 256, 0, stream>>>(XMC, PB + 2560, nullptr, XDBL, 4096, 48, 512,
                                  512, 1, 512, 1, 48, 1, 2097152, 0, BRS, 0,
                                  196608, 0, 0, 1.f, 0, nullptr);
  }
  // 9) dt = softplus(...); pack (delta, u) float2 -> DU
  {
    dim3 g(64, 8, 3);
    gemm_k<<<g, 256, 0, stream>>>(XDBL, PB + 27136, PB + 35328, (float*)DU,
                                  4096, 512, 16, 48, 1, 16, 1, 512, 1,
                                  196608, 0, BRS, 0, 2097152, 0, BRS,
                                  1.f, 3, XMC);
  }

  // 10) chunked selective scan -> Y bf16
  scanA_k<<<dim3(384, NCH), 256, 0, stream>>>(DU, XDBL, PB, SE, PC);
  scanB_k<<<384, 256, 0, stream>>>(SE, PC, SI);
  scanC_k<<<dim3(384, NCH), 256, 0, stream>>>(DU, XDBL, ZS, PB, SI, Y);

  // 11) combine -> COMBB bf16
  combine_k<<<8192, 256, 0, stream>>>(Y, COMBB);

  // 12) mamba out projection -> XMBB bf16
  bgemm(COMBB, OUTWB, nullptr, nullptr, XMBB, 4096, 256, 512, 512, 512, 256,
        1, 1, 0, 0, 0, 0, 0, 0, 1.f, 0);

  // 13) conv1 again (MFMA, NHWC bf16) + relu -> XM2B bf16
  conv_mfma_k<<<dim3(64, 4), 256, 0, stream>>>(XMBB, WCONV, p1b, nullptr, XM2B, 1);

  // 14) proj2 + relu -> XPB bf16
  bgemm(XM2B, P2WB, p2b, nullptr, XPB, 4096, 256, 256, 256, 256, 256,
        1, 1, 0, 0, 0, 0, 0, 0, 1.f, 1);

  // 15) fc1 -> XF f32
  bgemm(XPB, FC1WB, fc1b, XF, nullptr, 4096, 256, 256, 256, 256, 256,
        1, 1, 0, 0, 0, 0, 0, 0, 1.f, 0);

  // 16) depthwise 3x3 + residual -> out
  dw_k<<<128, 256, 0, stream>>>(XF, dww, dwb, x, out);
}

// Round 5
// 659.078 us; speedup vs baseline: 3.0663x; 1.2161x over previous
//
#include <hip/hip_runtime.h>

// ---------------------------------------------------------------------------
// Att_MambaLayer: bf16-MFMA GEMMs + MFMA convs + chunked scan (4-lane layout).
// B=4, C=256, H=W=32, N=l=1024, NH=2, dh=128, DI=512, DS=16, DTR=16.
// ---------------------------------------------------------------------------

#define LOG2E 1.4426950408889634f
#define NCH 16
#define LCH 64

typedef unsigned short u16;
typedef unsigned int u32;
typedef __attribute__((ext_vector_type(8))) short bf16x8;
typedef __attribute__((ext_vector_type(4))) float f32x4;

__device__ __forceinline__ u16 f2b(float f) {
  u32 u = __builtin_bit_cast(u32, f);
  u32 r = (u + 0x7fffu + ((u >> 16) & 1u)) >> 16;
  return (u16)r;
}
__device__ __forceinline__ float b2f(u16 h) {
  u32 u = ((u32)h) << 16;
  return __builtin_bit_cast(float, u);
}

// DPP add: p += p[lane ^ mask] within quad (pure VALU)
#define DPP_ADD(p, ctrl)                                                   \
  (p) += __builtin_bit_cast(float, __builtin_amdgcn_update_dpp(            \
             0, __builtin_bit_cast(int, (p)), ctrl, 0xF, 0xF, true))

static const long BRS = 44544;

// ---- param packing --------------------------------------------------------
__global__ __launch_bounds__(256) void pack_branch_k(
    float* __restrict__ dst, const float* __restrict__ cw,
    const float* __restrict__ cb, const float* __restrict__ xpw,
    const float* __restrict__ dtw, const float* __restrict__ dtb,
    const float* __restrict__ Alog, const float* __restrict__ Dv) {
  int t = blockIdx.x * 256 + threadIdx.x;
  if (t < 2048) dst[t] = cw[t];
  else if (t < 2560) dst[t] = cb[t - 2048];
  else if (t < 27136) dst[t] = xpw[t - 2560];
  else if (t < 35328) dst[t] = dtw[t - 27136];
  else if (t < 35840) dst[t] = dtb[t - 35328];
  else if (t < 44032) dst[t] = -expf(Alog[t - 35840]) * LOG2E;
  else if (t < 44544) dst[t] = Dv[t - 44032];
}

__global__ __launch_bounds__(256) void pack_wb_k(
    const float* __restrict__ qw, const float* __restrict__ kw,
    const float* __restrict__ vw, const float* __restrict__ ow,
    const float* __restrict__ inw, const float* __restrict__ outw,
    const float* __restrict__ p2w, const float* __restrict__ fc1w,
    const float* __restrict__ qb, const float* __restrict__ kb,
    const float* __restrict__ vb, u16* __restrict__ WB,
    float* __restrict__ QBIAS) {
  int t = blockIdx.x * 256 + threadIdx.x;   // < 787,200
  if (t < 65536) WB[t] = f2b(qw[t]);
  else if (t < 131072) WB[t] = f2b(kw[t - 65536]);
  else if (t < 196608) WB[t] = f2b(vw[t - 131072]);
  else if (t < 262144) WB[t] = f2b(ow[t - 196608]);
  else if (t < 524288) WB[t] = f2b(inw[t - 262144]);
  else if (t < 655360) WB[t] = f2b(outw[t - 524288]);
  else if (t < 720896) WB[t] = f2b(p2w[t - 655360]);
  else if (t < 786432) WB[t] = f2b(fc1w[t - 720896]);
  else if (t < 787200) {
    int i = t - 786432;
    QBIAS[i] = (i < 256) ? qb[i] : (i < 512 ? kb[i - 256] : vb[i - 512]);
  }
}

// conv weight pack: wc[co][(kh*3+kw)*256+ci] = w[co][ci][kh][kw]
__global__ __launch_bounds__(256) void pack_wc_k(const float* __restrict__ w,
                                                 u16* __restrict__ wc) {
  int t = blockIdx.x * 256 + threadIdx.x;   // < 589,824
  int ci = t & 255, khw = (t >> 8) % 9, co = t / 2304;
  wc[t] = f2b(w[co * 2304 + ci * 9 + khw]);
}

// x input -> shuffled NHWC bf16 (the x_flat permutation)
__global__ __launch_bounds__(256) void xin_k(const float* __restrict__ x,
                                             u16* __restrict__ xin) {
  int t = blockIdx.x * 256 + threadIdx.x;   // < 1,048,576
  int ci = t & 255, w = (t >> 8) & 31, h = (t >> 13) & 31, b = t >> 18;
  int idx = ci * 32 + h;
  xin[t] = f2b(x[((long)b << 18) + ((long)(idx & 255) << 10) +
                 ((idx >> 8) << 5) + w]);
}

// ---- MFMA 3x3 conv --------------------------------------------------------
__global__ __launch_bounds__(256, 2) void conv_mfma_k(
    const u16* __restrict__ in, const u16* __restrict__ wc,
    const float* __restrict__ bias, float* __restrict__ outF,
    u16* __restrict__ outH, int relu) {
  __shared__ u16 ldsA[4][64][8];
  __shared__ u16 ldsB[4][64][8];
  int m0 = blockIdx.x * 64, n0 = blockIdx.y * 64;
  int tid = threadIdx.x;
  int lane = tid & 63, wv = tid >> 6;
  int row = tid & 63, k8 = tid >> 6;
  int l = m0 + row;
  int h = (l >> 5) & 31, w = l & 31;
  int rlo = lane & 15, khl = lane >> 4;
  f32x4 acc[4];
  #pragma unroll
  for (int n = 0; n < 4; ++n) acc[n] = (f32x4){0.f, 0.f, 0.f, 0.f};
  for (int t = 0; t < 72; ++t) {
    int kh = t / 24, r = t % 24, kw = r >> 3, ci0 = (r & 7) << 5;
    __syncthreads();
    bf16x8 av = (bf16x8){0, 0, 0, 0, 0, 0, 0, 0};
    int hh = h + kh - 1, ww = w + kw - 1;
    if ((unsigned)hh < 32u && (unsigned)ww < 32u)
      av = *(const bf16x8*)&in[(long)(l + (kh - 1) * 32 + (kw - 1)) * 256 +
                               ci0 + k8 * 8];
    *(bf16x8*)&ldsA[k8][row][0] = av;
    *(bf16x8*)&ldsB[k8][row][0] =
        *(const bf16x8*)&wc[(long)(n0 + row) * 2304 + t * 32 + k8 * 8];
    __syncthreads();
    bf16x8 af = *(const bf16x8*)&ldsA[khl][wv * 16 + rlo][0];
    #pragma unroll
    for (int n = 0; n < 4; ++n) {
      bf16x8 bf = *(const bf16x8*)&ldsB[khl][n * 16 + rlo][0];
      acc[n] = __builtin_amdgcn_mfma_f32_16x16x32_bf16(af, bf, acc[n], 0, 0, 0);
    }
  }
  int rowb = (lane >> 4) * 4;
  #pragma unroll
  for (int n = 0; n < 4; ++n) {
    int gn = n0 + n * 16 + rlo;
    float bv = bias[gn];
    #pragma unroll
    for (int j = 0; j < 4; ++j) {
      int gm = m0 + wv * 16 + rowb + j;
      float v = acc[n][j] + bv;
      if (relu) v = fmaxf(v, 0.f);
      long oi = (long)gm * 256 + gn;
      if (outH) outH[oi] = f2b(v);
      else outF[oi] = v;
    }
  }
}

// ---- LayerNorm rows of 256 -> bf16 (wave per row) -------------------------
__global__ __launch_bounds__(256) void layernorm_k(const float* __restrict__ x,
                                                   const float* __restrict__ w,
                                                   const float* __restrict__ b,
                                                   u16* __restrict__ o) {
  int row = blockIdx.x * 4 + (threadIdx.x >> 6);
  int lane = threadIdx.x & 63;
  float4 v = ((const float4*)(x + (long)row * 256))[lane];
  float s = v.x + v.y + v.z + v.w;
  #pragma unroll
  for (int m = 32; m; m >>= 1) s += __shfl_xor(s, m);
  float mean = s * (1.f / 256.f);
  float4 dv = {v.x - mean, v.y - mean, v.z - mean, v.w - mean};
  float vs = dv.x * dv.x + dv.y * dv.y + dv.z * dv.z + dv.w * dv.w;
  #pragma unroll
  for (int m = 32; m; m >>= 1) vs += __shfl_xor(vs, m);
  float inv = rsqrtf(vs * (1.f / 256.f) + 1e-5f);
  float4 wv = ((const float4*)w)[lane];
  float4 bv = ((const float4*)b)[lane];
  u32 lo = (u32)f2b(dv.x * inv * wv.x + bv.x) |
           ((u32)f2b(dv.y * inv * wv.y + bv.y) << 16);
  u32 hi = (u32)f2b(dv.z * inv * wv.z + bv.z) |
           ((u32)f2b(dv.w * inv * wv.w + bv.w) << 16);
  ((uint2*)(o + (long)row * 256))[lane] = make_uint2(lo, hi);
}

// ---- softmax rows of 1024: f32 in, bf16 out (wave per row) ----------------
__global__ __launch_bounds__(256) void softmax_k(const float* __restrict__ S,
                                                 u16* __restrict__ P) {
  int row = blockIdx.x * 4 + (threadIdx.x >> 6);
  int lane = threadIdx.x & 63;
  const float4* p = (const float4*)(S + (long)row * 1024);
  float4 v[4];
  float m = -1e30f;
  #pragma unroll
  for (int i = 0; i < 4; ++i) {
    v[i] = p[lane * 4 + i];
    m = fmaxf(m, fmaxf(fmaxf(v[i].x, v[i].y), fmaxf(v[i].z, v[i].w)));
  }
  #pragma unroll
  for (int q = 32; q; q >>= 1) m = fmaxf(m, __shfl_xor(m, q));
  float s = 0.f;
  #pragma unroll
  for (int i = 0; i < 4; ++i) {
    v[i].x = expf(v[i].x - m); v[i].y = expf(v[i].y - m);
    v[i].z = expf(v[i].z - m); v[i].w = expf(v[i].w - m);
    s += v[i].x + v[i].y + v[i].z + v[i].w;
  }
  #pragma unroll
  for (int q = 32; q; q >>= 1) s += __shfl_xor(s, q);
  float inv = 1.f / s;
  uint2* q2 = (uint2*)(P + (long)row * 1024);
  #pragma unroll
  for (int i = 0; i < 4; ++i) {
    u32 lo = (u32)f2b(v[i].x * inv) | ((u32)f2b(v[i].y * inv) << 16);
    u32 hi = (u32)f2b(v[i].z * inv) | ((u32)f2b(v[i].w * inv) << 16);
    q2[lane * 4 + i] = make_uint2(lo, hi);
  }
}

// ---- bf16 MFMA GEMM: Out = act(alpha * A @ B^T + bias) --------------------
__global__ __launch_bounds__(256, 2) void bgemm_k(
    const u16* __restrict__ A, const u16* __restrict__ B,
    const float* __restrict__ bias, float* __restrict__ OutF,
    u16* __restrict__ OutH, int M, int N, int K,
    int lda, int ldb, int ldo, int zdiv,
    long a_zb, long a_zh, long b_zb, long b_zh, long o_zb, long o_zh,
    float alpha, int act) {
  __shared__ u16 ldsA[4][128][8];
  __shared__ u16 ldsB[4][128][8];
  int z = blockIdx.z, zb = z / zdiv, zh = z - zb * zdiv;
  const u16* Ab = A + zb * a_zb + zh * a_zh;
  const u16* Bb = B + zb * b_zb + zh * b_zh;
  long ob = zb * o_zb + zh * o_zh;
  int m0 = blockIdx.x * 128, n0 = blockIdx.y * 128;
  int tid = threadIdx.x;
  int lane = tid & 63, wv = tid >> 6;
  int wr = wv >> 1, wc = wv & 1;
  int r1 = tid & 127, h1 = tid >> 7;
  int r2 = r1, h2 = h1 + 2;
  const u16* a1 = Ab + (long)(m0 + r1) * lda + h1 * 8;
  const u16* a2 = Ab + (long)(m0 + r2) * lda + h2 * 8;
  const u16* b1 = Bb + (long)(n0 + r1) * ldb + h1 * 8;
  const u16* b2 = Bb + (long)(n0 + r2) * ldb + h2 * 8;

  f32x4 acc[4][4];
  #pragma unroll
  for (int i = 0; i < 4; ++i)
    #pragma unroll
    for (int j = 0; j < 4; ++j) acc[i][j] = (f32x4){0.f, 0.f, 0.f, 0.f};

  bf16x8 ra1 = *(const bf16x8*)a1;
  bf16x8 ra2 = *(const bf16x8*)a2;
  bf16x8 rb1 = *(const bf16x8*)b1;
  bf16x8 rb2 = *(const bf16x8*)b2;

  int nt = K >> 5;
  int kh = lane >> 4, rlo = lane & 15;
  for (int t = 0; t < nt; ++t) {
    __syncthreads();
    *(bf16x8*)&ldsA[h1][r1][0] = ra1;
    *(bf16x8*)&ldsA[h2][r2][0] = ra2;
    *(bf16x8*)&ldsB[h1][r1][0] = rb1;
    *(bf16x8*)&ldsB[h2][r2][0] = rb2;
    if (t + 1 < nt) {
      int ko = (t + 1) << 5;
      ra1 = *(const bf16x8*)(a1 + ko);
      ra2 = *(const bf16x8*)(a2 + ko);
      rb1 = *(const bf16x8*)(b1 + ko);
      rb2 = *(const bf16x8*)(b2 + ko);
    }
    __syncthreads();
    bf16x8 af[4], bfr[4];
    #pragma unroll
    for (int m = 0; m < 4; ++m)
      af[m] = *(const bf16x8*)&ldsA[kh][wr * 64 + m * 16 + rlo][0];
    #pragma unroll
    for (int n = 0; n < 4; ++n)
      bfr[n] = *(const bf16x8*)&ldsB[kh][wc * 64 + n * 16 + rlo][0];
    #pragma unroll
    for (int m = 0; m < 4; ++m)
      #pragma unroll
      for (int n = 0; n < 4; ++n)
        acc[m][n] = __builtin_amdgcn_mfma_f32_16x16x32_bf16(af[m], bfr[n],
                                                            acc[m][n], 0, 0, 0);
  }
  int rowb = (lane >> 4) * 4;
  #pragma unroll
  for (int m = 0; m < 4; ++m) {
    #pragma unroll
    for (int n = 0; n < 4; ++n) {
      int gn = n0 + wc * 64 + n * 16 + rlo;
      float bv = bias ? bias[gn] : 0.f;
      #pragma unroll
      for (int j = 0; j < 4; ++j) {
        int gm = m0 + wr * 64 + m * 16 + rowb + j;
        float v = acc[m][n][j] * alpha + bv;
        if (act == 1) v = fmaxf(v, 0.f);
        long oi = ob + (long)gm * ldo + gn;
        if (OutH) OutH[oi] = f2b(v);
        else OutF[oi] = v;
      }
    }
  }
}

// ---- V transpose ----------------------------------------------------------
__global__ __launch_bounds__(256) void vt_k(const u16* __restrict__ qkv,
                                            u16* __restrict__ vt) {
  int t = blockIdx.x * 256 + threadIdx.x;    // < 1,048,576
  int j = t & 1023, d = (t >> 10) & 127, bh = t >> 17;
  int b = bh >> 1, h = bh & 1;
  vt[t] = qkv[((long)(b * 1024 + j)) * 768 + 512 + h * 128 + d];
}

// ---- x_att permute --------------------------------------------------------
__global__ __launch_bounds__(256) void xatt_k(const float* __restrict__ hs,
                                              u16* __restrict__ xa) {
  int t = blockIdx.x * 256 + threadIdx.x;    // < 1,048,576
  int dm = t & 255, l = (t >> 8) & 1023, b = t >> 18;
  xa[t] = f2b(hs[((long)b << 18) + dm * 1024 + l]);
}

// ---- branch sequence index map --------------------------------------------
__device__ __forceinline__ int brmap(int br, int j) {
  if (br == 0) return j;
  if (br == 1) return 1023 - j;
  return ((j & 15) << 6) | (j >> 4);
}

// ---- causal conv1d (k=4) + silu; silu(z) -> bf16 --------------------------
__global__ __launch_bounds__(256) void cconv_k(const float* __restrict__ xz,
                                               const float* __restrict__ pk,
                                               float* __restrict__ xmc,
                                               u16* __restrict__ zs) {
  long t = (long)blockIdx.x * 256 + threadIdx.x;   // < 6,291,456
  int d = (int)(t & 511);
  long r = t >> 9;
  int j = (int)(r & 1023);
  int bb = (int)(r >> 10);
  int b = bb & 3, br = bb >> 2;
  const float* pb = pk + (long)br * BRS;
  float acc = pb[2048 + d];
  #pragma unroll
  for (int tap = 0; tap < 4; ++tap) {
    int jj = j - 3 + tap;
    if (jj >= 0) {
      int l = brmap(br, jj);
      acc = fmaf(xz[(((long)b << 10) + l) * 1024 + d], pb[d * 4 + tap], acc);
    }
  }
  float sig = 1.f / (1.f + expf(-acc));
  xmc[t] = acc * sig;
  int l = brmap(br, j);
  float zv = xz[(((long)b << 10) + l) * 1024 + 512 + d];
  zs[t] = f2b(zv / (1.f + expf(-zv)));
}

// ---- f32 SIMT GEMM (small shapes; act3 packs (delta,u) float2) ------------
__global__ __launch_bounds__(256) void gemm_k(
    const float* __restrict__ A, const float* __restrict__ B,
    const float* __restrict__ bias, float* __restrict__ Out,
    int M, int N, int K,
    int a_sm, int a_sk, int b_sn, int b_sk, int o_sm,
    int zdiv, long a_zb, long a_zh, long b_zb, long b_zh, long o_zb, long o_zh,
    long bias_zb, float alpha, int act, const float* __restrict__ Aux) {
  int z = blockIdx.z, zb = z / zdiv, zh = z % zdiv;
  const float* Ab = A + zb * a_zb + zh * a_zh;
  const float* Bb = B + zb * b_zb + zh * b_zh;
  const float* biasb = bias ? (bias + zb * bias_zb) : nullptr;
  long oo = zb * o_zb + zh * o_zh;
  __shared__ float As[16][68];
  __shared__ float Bs[16][68];
  int m0 = blockIdx.x * 64, n0 = blockIdx.y * 64;
  int tid = threadIdx.x;
  int tm = tid >> 4, tn = tid & 15;
  float acc[4][4] = {};
  for (int k0 = 0; k0 < K; k0 += 16) {
    #pragma unroll
    for (int it = 0; it < 4; ++it) {
      int i = tid + it * 256;
      if (a_sk == 1) {
        int rr = i >> 4, kk = i & 15;
        int gm = m0 + rr, gk = k0 + kk;
        float av = 0.f;
        if (gm < M && gk < K) av = Ab[(long)gm * a_sm + gk];
        As[kk][rr] = av;
      } else {
        int rr = i & 63, kk = i >> 6;
        int gm = m0 + rr, gk = k0 + kk;
        float av = 0.f;
        if (gm < M && gk < K) av = Ab[(long)gm * a_sm + (long)gk * a_sk];
        As[kk][rr] = av;
      }
      if (b_sk == 1) {
        int rr = i >> 4, kk = i & 15;
        int gn = n0 + rr, gk = k0 + kk;
        float bv = 0.f;
        if (gn < N && gk < K) bv = Bb[(long)gn * b_sn + gk];
        Bs[kk][rr] = bv;
      } else {
        int rr = i & 63, kk = i >> 6;
        int gn = n0 + rr, gk = k0 + kk;
        float bv = 0.f;
        if (gn < N && gk < K) bv = Bb[(long)gn * b_sn + (long)gk * b_sk];
        Bs[kk][rr] = bv;
      }
    }
    __syncthreads();
    #pragma unroll
    for (int kk = 0; kk < 16; ++kk) {
      float ar[4], br_[4];
      #pragma unroll
      for (int q = 0; q < 4; ++q) ar[q] = As[kk][tm * 4 + q];
      #pragma unroll
      for (int q = 0; q < 4; ++q) br_[q] = Bs[kk][tn * 4 + q];
      #pragma unroll
      for (int qi = 0; qi < 4; ++qi)
        #pragma unroll
        for (int qj = 0; qj < 4; ++qj)
          acc[qi][qj] = fmaf(ar[qi], br_[qj], acc[qi][qj]);
    }
    __syncthreads();
  }
  #pragma unroll
  for (int qi = 0; qi < 4; ++qi) {
    int gm = m0 + tm * 4 + qi;
    if (gm >= M) continue;
    #pragma unroll
    for (int qj = 0; qj < 4; ++qj) {
      int gn = n0 + tn * 4 + qj;
      if (gn >= N) continue;
      float v = acc[qi][qj] * alpha + (biasb ? biasb[gn] : 0.f);
      long oid = oo + (long)gm * o_sm + gn;
      if (act == 3) {
        float sp = (v > 30.f) ? v : log1pf(expf(v));
        ((float2*)Out)[oid] = make_float2(sp, Aux[oid]);
      } else {
        if (act == 1) v = fmaxf(v, 0.f);
        else if (act == 2) v = (v > 30.f) ? v : log1pf(expf(v));
        Out[oid] = v;
      }
    }
  }
}

// ---- chunked selective scan, 4 lanes/row x 4 states/lane ------------------
// grid (96, NCH): block = 4 waves, wave covers 16 consecutive d.
// blockIdx.x = bb*8 + dch; lane: q=lane&3 (states n=q*4..q*4+3), dl=lane>>2.

__global__ __launch_bounds__(256) void scanA_k(
    const float2* __restrict__ du, const float* __restrict__ xdbl,
    const float* __restrict__ pk, float* __restrict__ SE,
    float* __restrict__ PC) {
  __shared__ float bs[LCH][16];
  int tid = threadIdx.x;
  int wv = tid >> 6, lane = tid & 63;
  int q = lane & 3, dl = lane >> 2;
  int bb = blockIdx.x >> 3, dch = blockIdx.x & 7;
  int br = bb >> 2, b = bb & 3;
  int d = dch * 64 + wv * 16 + dl;
  int c = blockIdx.y;
  long xdb = (long)br * 196608 + (long)b * 49152 + (long)(c * LCH) * 48;
  {
    int j = tid >> 2, g = tid & 3;   // LCH*4 = 256 float4s
    *(float4*)&bs[j][g * 4] = *(const float4*)&xdbl[xdb + j * 48 + 16 + g * 4];
  }
  __syncthreads();
  const float* pb = pk + (long)br * BRS;
  float4 Aln = *(const float4*)&pb[35840 + d * 16 + q * 4];
  long obase = ((long)bb << 19) + (long)(c * LCH) * 512 + d;
  const float2* pdu = du + obase;
  float4 s = {0.f, 0.f, 0.f, 0.f};
  float S = 0.f;
  #pragma unroll 4
  for (int jl = 0; jl < LCH; ++jl) {
    float2 dv = pdu[(long)jl * 512];
    float w = dv.x * dv.y;
    float4 Bv = *(const float4*)&bs[jl][q * 4];
    s.x = fmaf(exp2f(dv.x * Aln.x), s.x, w * Bv.x);
    s.y = fmaf(exp2f(dv.x * Aln.y), s.y, w * Bv.y);
    s.z = fmaf(exp2f(dv.x * Aln.z), s.z, w * Bv.z);
    s.w = fmaf(exp2f(dv.x * Aln.w), s.w, w * Bv.w);
    S += dv.x;
  }
  long si = ((((long)bb) * NCH + c) * 512 + d) * 16 + q * 4;
  *(float4*)&SE[si] = s;
  float4 P = {exp2f(Aln.x * S), exp2f(Aln.y * S),
              exp2f(Aln.z * S), exp2f(Aln.w * S)};
  *(float4*)&PC[si] = P;
}

__global__ __launch_bounds__(256) void scanB_k(const float* __restrict__ SE,
                                               const float* __restrict__ PC,
                                               float* __restrict__ SI) {
  long t = (long)blockIdx.x * 256 + threadIdx.x;   // < 98,304
  int n = (int)(t & 15);
  int d = (int)((t >> 4) & 511);
  int bb = (int)(t >> 13);
  float run = 0.f;
  for (int c = 0; c < NCH; ++c) {
    long si = (((long)bb * NCH + c) * 512 + d) * 16 + n;
    SI[si] = run;
    run = fmaf(PC[si], run, SE[si]);
  }
}

__global__ __launch_bounds__(256) void scanC_k(
    const float2* __restrict__ du, const float* __restrict__ xdbl,
    const u16* __restrict__ zs, const float* __restrict__ pk,
    const float* __restrict__ SI, u16* __restrict__ y) {
  __shared__ float bcs[LCH][32];
  int tid = threadIdx.x;
  int wv = tid >> 6, lane = tid & 63;
  int q = lane & 3, dl = lane >> 2;
  int bb = blockIdx.x >> 3, dch = blockIdx.x & 7;
  int br = bb >> 2, b = bb & 3;
  int d = dch * 64 + wv * 16 + dl;
  int c = blockIdx.y;
  long xdb = (long)br * 196608 + (long)b * 49152 + (long)(c * LCH) * 48;
  #pragma unroll
  for (int i = 0; i < 2; ++i) {
    int idx = tid + i * 256;                 // LCH*8 = 512 float4s
    int j = idx >> 3, g = idx & 7;
    *(float4*)&bcs[j][g * 4] = *(const float4*)&xdbl[xdb + j * 48 + 16 + g * 4];
  }
  __syncthreads();
  const float* pb = pk + (long)br * BRS;
  float4 Aln = *(const float4*)&pb[35840 + d * 16 + q * 4];
  float Dv = pb[44032 + d];
  long obase = ((long)bb << 19) + (long)(c * LCH) * 512 + d;
  long si = ((((long)bb) * NCH + c) * 512 + d) * 16 + q * 4;
  float4 s = *(const float4*)&SI[si];
  const float2* pdu = du + obase;
  const u16* pzs = zs + obase;
  u16* py = y + obase;
  #pragma unroll 4
  for (int jl = 0; jl < LCH; ++jl) {
    float2 dv = pdu[(long)jl * 512];
    float w = dv.x * dv.y;
    float4 Bv = *(const float4*)&bcs[jl][q * 4];
    float4 Cv = *(const float4*)&bcs[jl][16 + q * 4];
    s.x = fmaf(exp2f(dv.x * Aln.x), s.x, w * Bv.x);
    s.y = fmaf(exp2f(dv.x * Aln.y), s.y, w * Bv.y);
    s.z = fmaf(exp2f(dv.x * Aln.z), s.z, w * Bv.z);
    s.w = fmaf(exp2f(dv.x * Aln.w), s.w, w * Bv.w);
    float p = s.x * Cv.x;
    p = fmaf(s.y, Cv.y, p);
    p = fmaf(s.z, Cv.z, p);
    p = fmaf(s.w, Cv.w, p);
    DPP_ADD(p, 0xB1);    // + lane^1
    DPP_ADD(p, 0x4E);    // + lane^2
    if (q == 0)
      py[(long)jl * 512] = f2b((p + Dv * dv.y) * b2f(pzs[(long)jl * 512]));
  }
}

// ---- combine 3 branch outputs -> COMBB bf16 (b,l,512) ---------------------
__global__ __launch_bounds__(256) void combine_k(const u16* __restrict__ y,
                                                 u16* __restrict__ comb) {
  long t = (long)blockIdx.x * 256 + threadIdx.x;   // < 2,097,152
  int d = (int)(t & 511);
  long r = t >> 9;
  int l = (int)(r & 1023);
  int b = (int)(r >> 10);
  int j2 = ((l & 63) << 4) | (l >> 6);
  float v = b2f(y[(((long)b << 10) + l) * 512 + d])
          + b2f(y[(((long)(4 + b) << 10) + (1023 - l)) * 512 + d])
          + b2f(y[(((long)(8 + b) << 10) + j2) * 512 + d]);
  comb[t] = f2b(v);
}

// ---- depthwise 3x3 conv + residual add, NCHW output -----------------------
__global__ __launch_bounds__(256) void dw_k(const float* __restrict__ xf,
                                            const float* __restrict__ dww,
                                            const float* __restrict__ dwb,
                                            const float* __restrict__ x,
                                            float* __restrict__ out) {
  int t = blockIdx.x;
  int b = t >> 5, h = t & 31;
  int c = threadIdx.x;
  float wv[9];
  #pragma unroll
  for (int k = 0; k < 9; ++k) wv[k] = dww[c * 9 + k];
  float bb = dwb[c];
  for (int w = 0; w < 32; ++w) {
    float acc = bb;
    #pragma unroll
    for (int kh = 0; kh < 3; ++kh) {
      int hh = h + kh - 1;
      if ((unsigned)hh >= 32u) continue;
      #pragma unroll
      for (int kw = 0; kw < 3; ++kw) {
        int ww = w + kw - 1;
        if ((unsigned)ww >= 32u) continue;
        acc = fmaf(xf[(((long)b << 10) + (hh << 5) + ww) * 256 + c],
                   wv[kh * 3 + kw], acc);
      }
    }
    long oi = (((long)b * 256 + c) * 32 + h) * 32 + w;
    out[oi] = acc + x[oi];
  }
}

// ---------------------------------------------------------------------------
extern "C" void kernel_launch(void* const* d_in, const int* in_sizes, int n_in,
                              void* d_out, int out_size, void* d_ws, size_t ws_size,
                              hipStream_t stream) {
  (void)in_sizes; (void)n_in; (void)out_size; (void)ws_size;
  const float* x    = (const float*)d_in[0];
  const float* p1w  = (const float*)d_in[1];
  const float* p1b  = (const float*)d_in[2];
  const float* p2w  = (const float*)d_in[3];
  const float* p2b  = (const float*)d_in[4];
  const float* nw   = (const float*)d_in[5];
  const float* nb   = (const float*)d_in[6];
  const float* qw   = (const float*)d_in[7];
  const float* qb   = (const float*)d_in[8];
  const float* kw   = (const float*)d_in[9];
  const float* kb   = (const float*)d_in[10];
  const float* vw   = (const float*)d_in[11];
  const float* vb   = (const float*)d_in[12];
  const float* ow   = (const float*)d_in[13];
  const float* ob   = (const float*)d_in[14];
  const float* fc1w = (const float*)d_in[15];
  const float* fc1b = (const float*)d_in[16];
  const float* dww  = (const float*)d_in[17];
  const float* dwb  = (const float*)d_in[18];
  const float* inw  = (const float*)d_in[19];
  const float* cw   = (const float*)d_in[20];
  const float* cb   = (const float*)d_in[21];
  const float* cbw  = (const float*)d_in[22];
  const float* cbb  = (const float*)d_in[23];
  const float* csw  = (const float*)d_in[24];
  const float* csb  = (const float*)d_in[25];
  const float* xpw  = (const float*)d_in[26];
  const float* xpbw = (const float*)d_in[27];
  const float* xpsw = (const float*)d_in[28];
  const float* dtw  = (const float*)d_in[29];
  const float* dtb  = (const float*)d_in[30];
  const float* dtbw = (const float*)d_in[31];
  const float* dtbb = (const float*)d_in[32];
  const float* dtsw = (const float*)d_in[33];
  const float* dtsb = (const float*)d_in[34];
  const float* Alog = (const float*)d_in[35];
  const float* Ablog= (const float*)d_in[36];
  const float* Aslog= (const float*)d_in[37];
  const float* Dv   = (const float*)d_in[38];
  const float* Dbv  = (const float*)d_in[39];
  const float* Dsv  = (const float*)d_in[40];
  const float* outw = (const float*)d_in[41];
  float* out = (float*)d_out;

  float* ws    = (float*)d_ws;
  float* PB    = ws;
  u16*   WCONV = (u16*)(ws + 140000);
  u16*   WB    = (u16*)(ws + 440000);
  float* QBIAS = ws + 840000;
  u16*   XINB  = (u16*)(ws + 850000);
  float* R     = ws + 1400000;
  // mamba/scan phase
  float*  XZ   = R;                         // dead after cconv
  float2* DU   = (float2*)R;                // written by dt-gemm
  float*  XMC  = R + 12700000;              // dead after dt-gemm ->
  u16*    Y    = (u16*)(R + 12700000);
  float*  SE   = R + 14300000;
  float*  PC   = R + 15900000;
  float*  SI   = R + 17500000;              // dead after scanC ->
  u16*   COMBB = (u16*)(R + 17500000);
  u16*    ZS   = (u16*)(R + 19100000);
  float*  XDBL = R + 25400000;
  // attn phase (dead before mamba phase)
  float* XCT   = R + 4300000;
  u16*   XCTB  = (u16*)(R + 5400000);
  u16*   QKVB  = (u16*)(R + 6000000);
  u16*   VT    = (u16*)(R + 7600000);
  float* SC    = R + 8200000;
  u16*   P     = (u16*)(R + 16600000);
  u16*   ATTB  = (u16*)(R + 18800000);
  float* HS    = R + 19400000;
  u16*   XATTB = (u16*)(R + 20500000);
  // tail phase
  u16*   XMBB  = (u16*)R;
  u16*   XM2B  = (u16*)(R + 600000);
  u16*   XPB   = (u16*)(R + 1200000);
  float* XF    = R + 1800000;

  u16* WQKVB = WB;
  u16* OWB   = WB + 196608;
  u16* INWB  = WB + 262144;
  u16* OUTWB = WB + 524288;
  u16* P2WB  = WB + 655360;
  u16* FC1WB = WB + 720896;

  auto bgemm = [&](const u16* A, const u16* Bm, const float* bias,
                   float* OutF, u16* OutH, int M, int N, int K,
                   int lda, int ldb, int ldo, int nz, int zdiv,
                   long a_zb, long a_zh, long b_zb, long b_zh,
                   long o_zb, long o_zh, float alpha, int act) {
    dim3 g(M / 128, N / 128, nz);
    bgemm_k<<<g, 256, 0, stream>>>(A, Bm, bias, OutF, OutH, M, N, K,
                                   lda, ldb, ldo, zdiv, a_zb, a_zh,
                                   b_zb, b_zh, o_zb, o_zh, alpha, act);
  };

  // 0) pack params
  pack_branch_k<<<174, 256, 0, stream>>>(PB, cw, cb, xpw, dtw, dtb, Alog, Dv);
  pack_branch_k<<<174, 256, 0, stream>>>(PB + BRS, cbw, cbb, xpbw, dtbw, dtbb, Ablog, Dbv);
  pack_branch_k<<<174, 256, 0, stream>>>(PB + 2 * BRS, csw, csb, xpsw, dtsw, dtsb, Aslog, Dsv);
  pack_wb_k<<<3075, 256, 0, stream>>>(qw, kw, vw, ow, inw, outw, p2w, fc1w,
                                      qb, kb, vb, WB, QBIAS);
  pack_wc_k<<<2304, 256, 0, stream>>>(p1w, WCONV);
  xin_k<<<4096, 256, 0, stream>>>(x, XINB);

  // 1) conv1 (MFMA, shuffled input) -> XCT f32; LN -> XCTB bf16
  conv_mfma_k<<<dim3(64, 4), 256, 0, stream>>>(XINB, WCONV, p1b, XCT, nullptr, 0);
  layernorm_k<<<1024, 256, 0, stream>>>(XCT, nw, nb, XCTB);

  // 2) fused QKV -> QKVB bf16 [4096][768]
  bgemm(XCTB, WQKVB, QBIAS, nullptr, QKVB, 4096, 768, 256, 256, 256, 768,
        1, 1, 0, 0, 0, 0, 0, 0, 1.f, 0);
  vt_k<<<4096, 256, 0, stream>>>(QKVB, VT);

  // 3) scores f32 = QK^T/sqrt(128); softmax -> P bf16
  bgemm(QKVB, QKVB + 256, nullptr, SC, nullptr, 1024, 1024, 128, 768, 768, 1024,
        8, 2, 786432, 128, 786432, 128, 2097152, 1048576,
        0.08838834764831845f, 0);
  softmax_k<<<2048, 256, 0, stream>>>(SC, P);

  // 4) att = P @ V^T -> ATTB bf16 [4096][256]
  bgemm(P, VT, nullptr, nullptr, ATTB, 1024, 128, 1024, 1024, 1024, 256,
        8, 2, 2097152, 1048576, 262144, 131072, 262144, 128, 1.f, 0);

  // 5) o-projection -> HS f32; permute -> XATTB bf16
  bgemm(ATTB, OWB, ob, HS, nullptr, 4096, 256, 256, 256, 256, 256,
        1, 1, 0, 0, 0, 0, 0, 0, 1.f, 0);
  xatt_k<<<4096, 256, 0, stream>>>(HS, XATTB);

  // 6) xz = x_att @ in_w^T -> XZ f32 [4][1024][1024]
  bgemm(XATTB, INWB, nullptr, XZ, nullptr, 1024, 1024, 256, 256, 256, 1024,
        4, 1, 262144, 0, 0, 0, 1048576, 0, 1.f, 0);

  // 7) causal conv1d + silu -> XMC; silu(z) -> ZS bf16
  cconv_k<<<24576, 256, 0, stream>>>(XZ, PB, XMC, ZS);

  // 8) x_dbl (f32 SIMT, N=48)
  {
    dim3 g(64, 1, 3);
    gemm_k<<<g, 256, 0, stream>>>(XMC, PB + 2560, nullptr, XDBL, 4096, 48, 512,
                                  512, 1, 512, 1, 48, 1, 2097152, 0, BRS, 0,
                                  196608, 0, 0, 1.f, 0, nullptr);
  }
  // 9) dt = softplus(...); pack (delta, u) float2 -> DU
  {
    dim3 g(64, 8, 3);
    gemm_k<<<g, 256, 0, stream>>>(XDBL, PB + 27136, PB + 35328, (float*)DU,
                                  4096, 512, 16, 48, 1, 16, 1, 512, 1,
                                  196608, 0, BRS, 0, 2097152, 0, BRS,
                                  1.f, 3, XMC);
  }

  // 10) chunked selective scan -> Y bf16
  scanA_k<<<dim3(96, NCH), 256, 0, stream>>>(DU, XDBL, PB, SE, PC);
  scanB_k<<<384, 256, 0, stream>>>(SE, PC, SI);
  scanC_k<<<dim3(96, NCH), 256, 0, stream>>>(DU, XDBL, ZS, PB, SI, Y);

  // 11) combine -> COMBB bf16
  combine_k<<<8192, 256, 0, stream>>>(Y, COMBB);

  // 12) mamba out projection -> XMBB bf16
  bgemm(COMBB, OUTWB, nullptr, nullptr, XMBB, 4096, 256, 512, 512, 512, 256,
        1, 1, 0, 0, 0, 0, 0, 0, 1.f, 0);

  // 13) conv1 again (MFMA, NHWC bf16) + relu -> XM2B bf16
  conv_mfma_k<<<dim3(64, 4), 256, 0, stream>>>(XMBB, WCONV, p1b, nullptr, XM2B, 1);

  // 14) proj2 + relu -> XPB bf16
  bgemm(XM2B, P2WB, p2b, nullptr, XPB, 4096, 256, 256, 256, 256, 256,
        1, 1, 0, 0, 0, 0, 0, 0, 1.f, 1);

  // 15) fc1 -> XF f32
  bgemm(XPB, FC1WB, fc1b, XF, nullptr, 4096, 256, 256, 256, 256, 256,
        1, 1, 0, 0, 0, 0, 0, 0, 1.f, 0);

  // 16) depthwise 3x3 + residual -> out
  dw_k<<<128, 256, 0, stream>>>(XF, dww, dwb, x, out);
}